// Round 1
// baseline (578.662 us; speedup 1.0000x reference)
//
#include <hip/hip_runtime.h>
#include <math.h>

#define S 256
#define C 128
#define NH 4
#define HID 32
#define NPOS (S*S)                       // 65536
#define SCALE 0.1767766952966369f        // 1/sqrt(32)
#define LN_EPS 1e-5f

// workspace layout in floats
#define WS_Q 0
#define WS_K (WS_Q + NH*S*S*HID)         // 8388608
#define WS_V (WS_K + NH*S*S*HID)         // 16777216
#define WS_G (WS_V + NH*S*S*HID)         // 25165824
#define WS_BIAS (WS_G + NH*S*S*HID)      // 33554432
#define WS_AO (WS_BIAS + NH*S*S)         // 33816576
// total floats = 42205184 (168.8 MB)

// ---------------------------------------------------------------------------
// Kernel 1: LayerNorm + fused projections (q,k,v,g,bias)
// grid 1024 blocks (64 positions each), 256 threads
// ---------------------------------------------------------------------------
__global__ __launch_bounds__(256)
void k_ln_proj(const float* __restrict__ x, const float* __restrict__ gamma,
               const float* __restrict__ beta,
               const float* __restrict__ Wq, const float* __restrict__ Wk,
               const float* __restrict__ Wv, const float* __restrict__ Wb,
               const float* __restrict__ Wg, const float* __restrict__ bg,
               float* __restrict__ ws)
{
    __shared__ float Az[128][64];   // z transposed: [channel][pos]  (32 KB)
    __shared__ float Bt[128][64];   // weight chunk: [k][col]        (32 KB)

    const int t   = threadIdx.x;
    const int blk = blockIdx.x;
    const int p0  = blk * 64;

    // ---- LayerNorm: 4 threads per row, 32 channels each ----
    {
        const int m  = t >> 2;   // 0..63 local position
        const int cp = t & 3;    // channel quarter
        float v[32];
        const float4* xr = (const float4*)(x + (size_t)(p0 + m) * C + cp * 32);
        float sum = 0.f, ssq = 0.f;
        #pragma unroll
        for (int q = 0; q < 8; ++q) {
            float4 f = xr[q];
            v[q*4+0]=f.x; v[q*4+1]=f.y; v[q*4+2]=f.z; v[q*4+3]=f.w;
            sum += f.x+f.y+f.z+f.w;
            ssq += f.x*f.x+f.y*f.y+f.z*f.z+f.w*f.w;
        }
        sum += __shfl_xor(sum, 1); ssq += __shfl_xor(ssq, 1);
        sum += __shfl_xor(sum, 2); ssq += __shfl_xor(ssq, 2);
        float mu  = sum * (1.f/128.f);
        float var = ssq * (1.f/128.f) - mu*mu;
        float rs  = rsqrtf(var + LN_EPS);
        #pragma unroll
        for (int e = 0; e < 32; ++e) {
            int c = cp*32 + e;
            Az[c][m] = (v[e]-mu)*rs*gamma[c] + beta[c];
        }
    }

    const int tm = t & 15;   // pos sub-tile   (4 positions)
    const int tn = t >> 4;   // col sub-tile   (4 cols)

    #pragma unroll 1
    for (int nc = 0; nc < 8; ++nc) {
        const float* Wsrc = (nc < 2) ? Wq : (nc < 4) ? Wk : (nc < 6) ? Wv : Wg;
        const int cb = (nc & 1) * 64;        // col base within matrix
        __syncthreads();
        // stage weight chunk [128 k][64 cols]
        {
            const int kb = t >> 4, nq = t & 15;
            #pragma unroll
            for (int s2 = 0; s2 < 8; ++s2) {
                int k = kb + s2*16;
                *(float4*)&Bt[k][nq*4] = *(const float4*)&Wsrc[k*128 + cb + nq*4];
            }
        }
        __syncthreads();

        float4 accr[4];
        #pragma unroll
        for (int mi = 0; mi < 4; ++mi) accr[mi] = make_float4(0.f,0.f,0.f,0.f);
        #pragma unroll 4
        for (int k = 0; k < 128; ++k) {
            float4 a = *(const float4*)&Az[k][tm*4];
            float4 b = *(const float4*)&Bt[k][tn*4];
            accr[0].x += a.x*b.x; accr[0].y += a.x*b.y; accr[0].z += a.x*b.z; accr[0].w += a.x*b.w;
            accr[1].x += a.y*b.x; accr[1].y += a.y*b.y; accr[1].z += a.y*b.z; accr[1].w += a.y*b.w;
            accr[2].x += a.z*b.x; accr[2].y += a.z*b.y; accr[2].z += a.z*b.z; accr[2].w += a.z*b.w;
            accr[3].x += a.w*b.x; accr[3].y += a.w*b.y; accr[3].z += a.w*b.z; accr[3].w += a.w*b.w;
        }

        // epilogue: scatter to [n][j][i][d] layout
        const int cc = cb + tn*4;            // col within matrix, 0..124
        const int nh = cc >> 5;
        const int d  = cc & 31;
        const int mm = nc >> 1;              // 0=q 1=k 2=v 3=g
        float* dst = ws + (mm==0 ? WS_Q : mm==1 ? WS_K : mm==2 ? WS_V : WS_G);
        float4 bgv = make_float4(0.f,0.f,0.f,0.f);
        if (mm == 3) bgv = *(const float4*)&bg[cc];
        #pragma unroll
        for (int mi = 0; mi < 4; ++mi) {
            int p = p0 + tm*4 + mi;
            int r = p >> 8, c2 = p & 255;
            size_t o = (((size_t)(nh*256 + c2))*256 + (size_t)r)*32 + d;
            float4 val = accr[mi];
            if (mm == 3) {
                val.x = 1.f/(1.f+__expf(-(val.x+bgv.x)));
                val.y = 1.f/(1.f+__expf(-(val.y+bgv.y)));
                val.z = 1.f/(1.f+__expf(-(val.z+bgv.z)));
                val.w = 1.f/(1.f+__expf(-(val.w+bgv.w)));
            }
            *(float4*)&dst[o] = val;
        }
    }

    // ---- bias projection: z @ Wb -> bias[n][i][j] ----
    __syncthreads();
    {
        const int mB = t & 63, nh = t >> 6;
        float sacc = 0.f;
        #pragma unroll 4
        for (int k = 0; k < 128; ++k) sacc += Az[k][mB] * Wb[k*4 + nh];
        ws[WS_BIAS + (size_t)nh*NPOS + p0 + mB] = sacc;
    }
}

// ---------------------------------------------------------------------------
// Kernel 2: attention per (head n, column j). grid 1024 blocks, 256 threads
// dots[i][k] = SCALE * sum_d Q[i][d]*K[k][d] + bias[n][i][k]
// softmax over k; out[i][d] = g[i][d] * sum_k attn * V[k][d]
// ---------------------------------------------------------------------------
__global__ __launch_bounds__(256)
void k_attn(float* __restrict__ ws)
{
    __shared__ float Kt[32][260];   // K transposed [d][k]   33.3 KB
    __shared__ float Qtc[32][20];   // Q chunk transposed [d][i_loc]
    __shared__ float Pl[16][260];   // exp(dots) chunk [i_loc][k]
    __shared__ float red[16][66];
    __shared__ float rowmax[16];
    __shared__ float rowinv[16];

    const int t = threadIdx.x;
    const int n = blockIdx.x >> 8;
    const int j = blockIdx.x & 255;
    const size_t base = ((size_t)(n*256 + j)) * (size_t)(S*HID);  // *8192 floats
    const float4* q4 = (const float4*)(ws + WS_Q + base);
    const float4* k4 = (const float4*)(ws + WS_K + base);
    const float4* v4 = (const float4*)(ws + WS_V + base);
    const float4* g4 = (const float4*)(ws + WS_G + base);
    const float* biasn = ws + WS_BIAS + (size_t)n*NPOS;
    float4* ao4 = (float4*)(ws + WS_AO);

    // stage K transposed: [i][d] -> Kt[d][i]
    #pragma unroll
    for (int s2 = 0; s2 < 8; ++s2) {
        int idx = s2*256 + t;
        int i = idx >> 3, dq = idx & 7;
        float4 kv = k4[idx];
        Kt[dq*4+0][i] = kv.x;
        Kt[dq*4+1][i] = kv.y;
        Kt[dq*4+2][i] = kv.z;
        Kt[dq*4+3][i] = kv.w;
    }
    __syncthreads();

    const int tm = t & 3;            // dots: 4 rows
    const int tn = t >> 2;           // dots: 4 cols (k), 0..63
    const int pv_i  = t >> 4;        // PV: row 0..15
    const int pv_kh = (t >> 3) & 1;  // PV: k half
    const int pv_dq = t & 7;         // PV: d quad

    #pragma unroll 1
    for (int ic = 0; ic < 16; ++ic) {
        const int i0c = ic * 16;
        // stage Q chunk transposed
        if (t < 128) {
            int il = t >> 3, dq = t & 7;
            float4 qv = q4[(size_t)(i0c + il)*8 + dq];
            Qtc[dq*4+0][il] = qv.x;
            Qtc[dq*4+1][il] = qv.y;
            Qtc[dq*4+2][il] = qv.z;
            Qtc[dq*4+3][il] = qv.w;
        }
        __syncthreads();

        // ---- dots: 4i x 4k per thread ----
        float4 accr[4];
        #pragma unroll
        for (int mi = 0; mi < 4; ++mi) accr[mi] = make_float4(0.f,0.f,0.f,0.f);
        #pragma unroll 4
        for (int d = 0; d < 32; ++d) {
            float4 a = *(const float4*)&Qtc[d][tm*4];
            float4 b = *(const float4*)&Kt[d][tn*4];
            accr[0].x += a.x*b.x; accr[0].y += a.x*b.y; accr[0].z += a.x*b.z; accr[0].w += a.x*b.w;
            accr[1].x += a.y*b.x; accr[1].y += a.y*b.y; accr[1].z += a.y*b.z; accr[1].w += a.y*b.w;
            accr[2].x += a.z*b.x; accr[2].y += a.z*b.y; accr[2].z += a.z*b.z; accr[2].w += a.z*b.w;
            accr[3].x += a.w*b.x; accr[3].y += a.w*b.y; accr[3].z += a.w*b.z; accr[3].w += a.w*b.w;
        }
        #pragma unroll
        for (int mi = 0; mi < 4; ++mi) {
            int ig = i0c + tm*4 + mi;
            float4 bv = *(const float4*)&biasn[(size_t)ig*256 + tn*4];
            accr[mi].x = accr[mi].x*SCALE + bv.x;
            accr[mi].y = accr[mi].y*SCALE + bv.y;
            accr[mi].z = accr[mi].z*SCALE + bv.z;
            accr[mi].w = accr[mi].w*SCALE + bv.w;
        }

        // ---- softmax over k (256 values per row, spread across 64 tn) ----
        #pragma unroll
        for (int mi = 0; mi < 4; ++mi) {
            float mx = fmaxf(fmaxf(accr[mi].x, accr[mi].y), fmaxf(accr[mi].z, accr[mi].w));
            red[tm*4+mi][tn] = mx;
        }
        __syncthreads();
        if (t < 16) {
            float mx = red[t][0];
            for (int kk = 1; kk < 64; ++kk) mx = fmaxf(mx, red[t][kk]);
            rowmax[t] = mx;
        }
        __syncthreads();
        #pragma unroll
        for (int mi = 0; mi < 4; ++mi) {
            float mx = rowmax[tm*4+mi];
            accr[mi].x = __expf(accr[mi].x - mx);
            accr[mi].y = __expf(accr[mi].y - mx);
            accr[mi].z = __expf(accr[mi].z - mx);
            accr[mi].w = __expf(accr[mi].w - mx);
            red[tm*4+mi][tn] = accr[mi].x+accr[mi].y+accr[mi].z+accr[mi].w;
        }
        __syncthreads();
        if (t < 16) {
            float sm = 0.f;
            for (int kk = 0; kk < 64; ++kk) sm += red[t][kk];
            rowinv[t] = 1.f / sm;
        }
        #pragma unroll
        for (int mi = 0; mi < 4; ++mi)
            *(float4*)&Pl[tm*4+mi][tn*4] = accr[mi];   // unnormalized exp
        __syncthreads();

        // ---- PV: out[i][d] = (1/rowsum) * sum_k P[i][k] * V[k][d], gated ----
        float4 o = make_float4(0.f,0.f,0.f,0.f);
        #pragma unroll 2
        for (int kb = 0; kb < 32; ++kb) {
            int k0 = pv_kh*128 + kb*4;
            float4 p  = *(const float4*)&Pl[pv_i][k0];
            float4 va = v4[(size_t)(k0+0)*8 + pv_dq];
            float4 vb = v4[(size_t)(k0+1)*8 + pv_dq];
            float4 vc = v4[(size_t)(k0+2)*8 + pv_dq];
            float4 vd = v4[(size_t)(k0+3)*8 + pv_dq];
            o.x += p.x*va.x + p.y*vb.x + p.z*vc.x + p.w*vd.x;
            o.y += p.x*va.y + p.y*vb.y + p.z*vc.y + p.w*vd.y;
            o.z += p.x*va.z + p.y*vb.z + p.z*vc.z + p.w*vd.z;
            o.w += p.x*va.w + p.y*vb.w + p.z*vc.w + p.w*vd.w;
        }
        o.x += __shfl_xor(o.x, 8);
        o.y += __shfl_xor(o.y, 8);
        o.z += __shfl_xor(o.z, 8);
        o.w += __shfl_xor(o.w, 8);
        if (pv_kh == 0) {
            int ig = i0c + pv_i;
            float inv = rowinv[pv_i];
            float4 gv = g4[(size_t)ig*8 + pv_dq];
            float4 res;
            res.x = o.x*inv*gv.x;
            res.y = o.y*inv*gv.y;
            res.z = o.z*inv*gv.z;
            res.w = o.w*inv*gv.w;
            ao4[((size_t)(ig*256 + j))*32 + n*8 + pv_dq] = res;
        }
        __syncthreads();
    }
}

// ---------------------------------------------------------------------------
// Kernel 3: output GEMM  [65536 x 128] @ Wo[128 x 128] + bo
// ---------------------------------------------------------------------------
__global__ __launch_bounds__(256)
void k_out(const float* __restrict__ ws, const float* __restrict__ Wo,
           const float* __restrict__ bo, float* __restrict__ out)
{
    __shared__ float At[128][64];
    __shared__ float Bt[128][64];
    const int t  = threadIdx.x;
    const int p0 = blockIdx.x * 64;
    {
        const int m = t >> 2, cp = t & 3;
        const float4* ar = (const float4*)(ws + WS_AO + (size_t)(p0+m)*128 + cp*32);
        #pragma unroll
        for (int q = 0; q < 8; ++q) {
            float4 f = ar[q];
            int c = cp*32 + q*4;
            At[c+0][m]=f.x; At[c+1][m]=f.y; At[c+2][m]=f.z; At[c+3][m]=f.w;
        }
    }
    const int tm = t & 15, tn = t >> 4;
    #pragma unroll 1
    for (int nc = 0; nc < 2; ++nc) {
        const int cb = nc * 64;
        __syncthreads();
        {
            const int kb = t >> 4, nq = t & 15;
            #pragma unroll
            for (int s2 = 0; s2 < 8; ++s2) {
                int k = kb + s2*16;
                *(float4*)&Bt[k][nq*4] = *(const float4*)&Wo[k*128 + cb + nq*4];
            }
        }
        __syncthreads();
        float4 accr[4];
        #pragma unroll
        for (int mi = 0; mi < 4; ++mi) accr[mi] = make_float4(0.f,0.f,0.f,0.f);
        #pragma unroll 4
        for (int k = 0; k < 128; ++k) {
            float4 a = *(const float4*)&At[k][tm*4];
            float4 b = *(const float4*)&Bt[k][tn*4];
            accr[0].x += a.x*b.x; accr[0].y += a.x*b.y; accr[0].z += a.x*b.z; accr[0].w += a.x*b.w;
            accr[1].x += a.y*b.x; accr[1].y += a.y*b.y; accr[1].z += a.y*b.z; accr[1].w += a.y*b.w;
            accr[2].x += a.z*b.x; accr[2].y += a.z*b.y; accr[2].z += a.z*b.z; accr[2].w += a.z*b.w;
            accr[3].x += a.w*b.x; accr[3].y += a.w*b.y; accr[3].z += a.w*b.z; accr[3].w += a.w*b.w;
        }
        float4 bov = *(const float4*)&bo[cb + tn*4];
        #pragma unroll
        for (int mi = 0; mi < 4; ++mi) {
            int p = p0 + tm*4 + mi;
            float4 r = accr[mi];
            r.x += bov.x; r.y += bov.y; r.z += bov.z; r.w += bov.w;
            *(float4*)&out[(size_t)p*128 + cb + tn*4] = r;
        }
    }
}

// ---------------------------------------------------------------------------
extern "C" void kernel_launch(void* const* d_in, const int* in_sizes, int n_in,
                              void* d_out, int out_size, void* d_ws, size_t ws_size,
                              hipStream_t stream) {
    const float* x     = (const float*)d_in[0];
    const float* gamma = (const float*)d_in[1];
    const float* beta  = (const float*)d_in[2];
    const float* Wq    = (const float*)d_in[3];
    const float* Wk    = (const float*)d_in[4];
    const float* Wv    = (const float*)d_in[5];
    const float* Wb    = (const float*)d_in[6];
    const float* Wg    = (const float*)d_in[7];
    const float* bg    = (const float*)d_in[8];
    const float* Wo    = (const float*)d_in[9];
    const float* bo    = (const float*)d_in[10];
    float* out = (float*)d_out;
    float* ws  = (float*)d_ws;

    k_ln_proj<<<1024, 256, 0, stream>>>(x, gamma, beta, Wq, Wk, Wv, Wb, Wg, bg, ws);
    k_attn<<<1024, 256, 0, stream>>>(ws);
    k_out<<<1024, 256, 0, stream>>>(ws, Wo, bo, out);
}

// Round 2
// 280.641 us; speedup vs baseline: 2.0619x; 2.0619x over previous
//
#include <hip/hip_runtime.h>
#include <hip/hip_bf16.h>
#include <math.h>

#define S 256
#define C 128
#define NH 4
#define HID 32
#define NPOS (S*S)                       // 65536
#define SCALE 0.1767766952966369f        // 1/sqrt(32)
#define LN_EPS 1e-5f

typedef short bf16x8 __attribute__((ext_vector_type(8)));
typedef float f32x4 __attribute__((ext_vector_type(4)));

__device__ __forceinline__ unsigned short f2bf(float f) {
    __hip_bfloat16 h = __float2bfloat16(f);
    return *reinterpret_cast<unsigned short*>(&h);
}
__device__ __forceinline__ float bf2f(unsigned short u) {
    union { unsigned int u32; float f; } c;
    c.u32 = ((unsigned int)u) << 16;
    return c.f;
}

// ---------------------------------------------------------------------------
// Kernel 1: LayerNorm + projections via bf16 MFMA.
// grid 1024 blocks (64 positions), 256 threads (4 waves).
// outputs: Q,K bf16 [n][j][i][d]; VT bf16 [n][j][d][i]; G fp32 [n][j][i][d];
//          BIAS fp32 [n][i][k]
// ---------------------------------------------------------------------------
__global__ __launch_bounds__(256)
void k_ln_proj(const float* __restrict__ x, const float* __restrict__ gamma,
               const float* __restrict__ beta,
               const float* __restrict__ Wq, const float* __restrict__ Wk,
               const float* __restrict__ Wv, const float* __restrict__ Wb,
               const float* __restrict__ Wg, const float* __restrict__ bg,
               unsigned short* __restrict__ Q, unsigned short* __restrict__ K,
               unsigned short* __restrict__ VT, float* __restrict__ G,
               float* __restrict__ BIAS)
{
    __shared__ unsigned short z_lds[64][136];   // [pos][chan], pad->stride 136
    __shared__ unsigned short wT[64][136];      // [col][k]

    const int t    = threadIdx.x;
    const int p0   = blockIdx.x * 64;
    const int lane = t & 63, w = t >> 6;
    const int l15  = lane & 15, quad = lane >> 4;

    // ---- LayerNorm (fp32), write z to LDS as bf16 ----
    {
        const int m  = t >> 2;
        const int cp = t & 3;
        float v[32];
        const float4* xr = (const float4*)(x + (size_t)(p0 + m) * C + cp * 32);
        float sum = 0.f, ssq = 0.f;
        #pragma unroll
        for (int q = 0; q < 8; ++q) {
            float4 f = xr[q];
            v[q*4+0]=f.x; v[q*4+1]=f.y; v[q*4+2]=f.z; v[q*4+3]=f.w;
            sum += f.x+f.y+f.z+f.w;
            ssq += f.x*f.x+f.y*f.y+f.z*f.z+f.w*f.w;
        }
        sum += __shfl_xor(sum, 1); ssq += __shfl_xor(ssq, 1);
        sum += __shfl_xor(sum, 2); ssq += __shfl_xor(ssq, 2);
        float mu  = sum * (1.f/128.f);
        float var = ssq * (1.f/128.f) - mu*mu;
        float rs  = rsqrtf(var + LN_EPS);
        #pragma unroll
        for (int e = 0; e < 32; ++e) {
            int c = cp*32 + e;
            z_lds[m][c] = f2bf((v[e]-mu)*rs*gamma[c] + beta[c]);
        }
    }

    #pragma unroll 1
    for (int nc = 0; nc < 8; ++nc) {
        const float* Wsrc = (nc < 2) ? Wq : (nc < 4) ? Wk : (nc < 6) ? Wv : Wg;
        const int cb = (nc & 1) * 64;
        __syncthreads();
        // stage wT[c][k] = bf16(Wsrc[k][cb+c]) : 2048 float4 loads
        #pragma unroll
        for (int r = 0; r < 8; ++r) {
            int idx4 = r*256 + t;
            int k = idx4 >> 4, cq = idx4 & 15;
            float4 f = *(const float4*)&Wsrc[k*128 + cb + cq*4];
            wT[cq*4+0][k] = f2bf(f.x);
            wT[cq*4+1][k] = f2bf(f.y);
            wT[cq*4+2][k] = f2bf(f.z);
            wT[cq*4+3][k] = f2bf(f.w);
        }
        __syncthreads();

        // wave w computes rows [w*16, w*16+16) x 64 cols
        f32x4 acc[4];
        #pragma unroll
        for (int nt = 0; nt < 4; ++nt) acc[nt] = (f32x4){0.f,0.f,0.f,0.f};
        #pragma unroll
        for (int kt = 0; kt < 4; ++kt) {
            bf16x8 a = *(const bf16x8*)&z_lds[w*16 + l15][kt*32 + quad*8];
            #pragma unroll
            for (int nt = 0; nt < 4; ++nt) {
                bf16x8 b = *(const bf16x8*)&wT[nt*16 + l15][kt*32 + quad*8];
                acc[nt] = __builtin_amdgcn_mfma_f32_16x16x32_bf16(a, b, acc[nt], 0, 0, 0);
            }
        }

        // epilogue scatter
        const int mm = nc >> 1;   // 0=q 1=k 2=v 3=g
        #pragma unroll
        for (int nt = 0; nt < 4; ++nt) {
            int cc = cb + nt*16 + l15;
            int nh = cc >> 5, d = cc & 31;
            float bgv = (mm == 3) ? bg[cc] : 0.f;
            #pragma unroll
            for (int reg = 0; reg < 4; ++reg) {
                int p = p0 + w*16 + quad*4 + reg;
                int i = p >> 8, j = p & 255;
                float val = acc[nt][reg];
                if (mm == 0) {
                    Q[(((size_t)(nh*256 + j))*256 + i)*32 + d] = f2bf(val);
                } else if (mm == 1) {
                    K[(((size_t)(nh*256 + j))*256 + i)*32 + d] = f2bf(val);
                } else if (mm == 2) {
                    VT[(((size_t)(nh*256 + j))*32 + d)*256 + i] = f2bf(val);
                } else {
                    float s = 1.f/(1.f + __expf(-(val + bgv)));
                    G[(((size_t)(nh*256 + j))*256 + i)*32 + d] = s;
                }
            }
        }
    }

    // ---- bias projection: z @ Wb -> BIAS[n][i][k] (fp32) ----
    {
        const int mB = t & 63, nh = t >> 6;
        float sacc = 0.f;
        #pragma unroll 4
        for (int k = 0; k < 128; ++k) sacc += bf2f(z_lds[mB][k]) * Wb[k*4 + nh];
        BIAS[(size_t)nh*NPOS + p0 + mB] = sacc;
    }
}

// ---------------------------------------------------------------------------
// Kernel 2: attention per (n, j). 256 threads, 4 independent waves, no barriers.
// ---------------------------------------------------------------------------
__global__ __launch_bounds__(256)
void k_attn(const unsigned short* __restrict__ Q, const unsigned short* __restrict__ K,
            const unsigned short* __restrict__ VT, const float* __restrict__ G,
            const float* __restrict__ BIAS, unsigned short* __restrict__ AO)
{
    __shared__ unsigned short P_lds[4][16*264];   // per-wave P strip, padded stride

    const int t    = threadIdx.x;
    const int n    = blockIdx.x >> 8;
    const int j    = blockIdx.x & 255;
    const int lane = t & 63, w = t >> 6;
    const int l15  = lane & 15, quad = lane >> 4;

    const size_t nb = (size_t)(n*256 + j);
    const unsigned short* qb  = Q  + nb*8192;   // [i][d]
    const unsigned short* kb  = K  + nb*8192;   // [k][d]
    const unsigned short* vtb = VT + nb*8192;   // [d][k]
    const float* gb    = G + nb*8192;           // [i][d]
    const float* biasn = BIAS + (size_t)n*NPOS; // [i][k]
    unsigned short* Pw = P_lds[w];

    #pragma unroll 1
    for (int itc = 0; itc < 4; ++itc) {
        const int i0 = w*64 + itc*16;

        // ---- S = Q Kt : one A-frag, 16 k-tiles ----
        bf16x8 a = *(const bf16x8*)(qb + (size_t)(i0 + l15)*32 + quad*8);
        f32x4 acc[16];
        #pragma unroll
        for (int kt = 0; kt < 16; ++kt) {
            bf16x8 b = *(const bf16x8*)(kb + (size_t)(kt*16 + l15)*32 + quad*8);
            acc[kt] = __builtin_amdgcn_mfma_f32_16x16x32_bf16(a, b, (f32x4){0.f,0.f,0.f,0.f}, 0, 0, 0);
        }

        // ---- scale + bias + row max (rows = quad*4+reg, cols spread over l15,kt) ----
        float mx[4] = {-1e30f, -1e30f, -1e30f, -1e30f};
        #pragma unroll
        for (int kt = 0; kt < 16; ++kt) {
            #pragma unroll
            for (int reg = 0; reg < 4; ++reg) {
                float bv = biasn[(size_t)(i0 + quad*4 + reg)*256 + kt*16 + l15];
                float v = acc[kt][reg]*SCALE + bv;
                acc[kt][reg] = v;
                mx[reg] = fmaxf(mx[reg], v);
            }
        }
        #pragma unroll
        for (int m = 1; m <= 8; m <<= 1) {
            #pragma unroll
            for (int reg = 0; reg < 4; ++reg)
                mx[reg] = fmaxf(mx[reg], __shfl_xor(mx[reg], m));
        }

        // ---- exp + row sum ----
        float sm[4] = {0.f, 0.f, 0.f, 0.f};
        #pragma unroll
        for (int kt = 0; kt < 16; ++kt) {
            #pragma unroll
            for (int reg = 0; reg < 4; ++reg) {
                float e = __expf(acc[kt][reg] - mx[reg]);
                acc[kt][reg] = e;
                sm[reg] += e;
            }
        }
        #pragma unroll
        for (int m = 1; m <= 8; m <<= 1) {
            #pragma unroll
            for (int reg = 0; reg < 4; ++reg)
                sm[reg] += __shfl_xor(sm[reg], m);
        }
        float rinv[4];
        #pragma unroll
        for (int reg = 0; reg < 4; ++reg) rinv[reg] = 1.f / sm[reg];

        // ---- P (unnormalized exp) -> LDS bf16, stride 264 ----
        #pragma unroll
        for (int kt = 0; kt < 16; ++kt) {
            #pragma unroll
            for (int reg = 0; reg < 4; ++reg)
                Pw[(quad*4 + reg)*264 + kt*16 + l15] = f2bf(acc[kt][reg]);
        }

        // ---- PV: out[i][d] = sum_k P[i][k] V[k][d] ----
        f32x4 o[2];
        o[0] = (f32x4){0.f,0.f,0.f,0.f};
        o[1] = (f32x4){0.f,0.f,0.f,0.f};
        #pragma unroll
        for (int kt8 = 0; kt8 < 8; ++kt8) {
            bf16x8 pa = *(const bf16x8*)(Pw + l15*264 + kt8*32 + quad*8);
            #pragma unroll
            for (int nt = 0; nt < 2; ++nt) {
                bf16x8 vb = *(const bf16x8*)(vtb + (size_t)(nt*16 + l15)*256 + kt8*32 + quad*8);
                o[nt] = __builtin_amdgcn_mfma_f32_16x16x32_bf16(pa, vb, o[nt], 0, 0, 0);
            }
        }

        // ---- gate, normalize, store bf16 AO[pos][n*32+d] ----
        #pragma unroll
        for (int nt = 0; nt < 2; ++nt) {
            #pragma unroll
            for (int reg = 0; reg < 4; ++reg) {
                int i = i0 + quad*4 + reg;
                float g = gb[(size_t)i*32 + nt*16 + l15];
                float res = o[nt][reg] * rinv[reg] * g;
                AO[((size_t)(i*256 + j))*128 + n*32 + nt*16 + l15] = f2bf(res);
            }
        }
    }
}

// ---------------------------------------------------------------------------
// Kernel 3: out = AO(bf16) @ Wo + bo, fp32 out. 64 rows/block.
// ---------------------------------------------------------------------------
__global__ __launch_bounds__(256)
void k_out(const unsigned short* __restrict__ AO, const float* __restrict__ Wo,
           const float* __restrict__ bo, float* __restrict__ out)
{
    __shared__ unsigned short wT[128][136];   // [col][k]

    const int t    = threadIdx.x;
    const int p0   = blockIdx.x * 64;
    const int lane = t & 63, w = t >> 6;
    const int l15  = lane & 15, quad = lane >> 4;

    // stage WoT: 4096 float4
    #pragma unroll
    for (int r = 0; r < 16; ++r) {
        int idx4 = r*256 + t;
        int k = idx4 >> 5, cq = idx4 & 31;
        float4 f = *(const float4*)&Wo[k*128 + cq*4];
        wT[cq*4+0][k] = f2bf(f.x);
        wT[cq*4+1][k] = f2bf(f.y);
        wT[cq*4+2][k] = f2bf(f.z);
        wT[cq*4+3][k] = f2bf(f.w);
    }
    __syncthreads();

    f32x4 acc[8];
    #pragma unroll
    for (int nt = 0; nt < 8; ++nt) acc[nt] = (f32x4){0.f,0.f,0.f,0.f};
    #pragma unroll
    for (int kt = 0; kt < 4; ++kt) {
        bf16x8 a = *(const bf16x8*)(AO + (size_t)(p0 + w*16 + l15)*128 + kt*32 + quad*8);
        #pragma unroll
        for (int nt = 0; nt < 8; ++nt) {
            bf16x8 b = *(const bf16x8*)&wT[nt*16 + l15][kt*32 + quad*8];
            acc[nt] = __builtin_amdgcn_mfma_f32_16x16x32_bf16(a, b, acc[nt], 0, 0, 0);
        }
    }
    #pragma unroll
    for (int nt = 0; nt < 8; ++nt) {
        float bov = bo[nt*16 + l15];
        #pragma unroll
        for (int reg = 0; reg < 4; ++reg) {
            int p = p0 + w*16 + quad*4 + reg;
            out[(size_t)p*128 + nt*16 + l15] = acc[nt][reg] + bov;
        }
    }
}

// ---------------------------------------------------------------------------
extern "C" void kernel_launch(void* const* d_in, const int* in_sizes, int n_in,
                              void* d_out, int out_size, void* d_ws, size_t ws_size,
                              hipStream_t stream) {
    (void)in_sizes; (void)n_in; (void)out_size; (void)ws_size;
    const float* x     = (const float*)d_in[0];
    const float* gamma = (const float*)d_in[1];
    const float* beta  = (const float*)d_in[2];
    const float* Wq    = (const float*)d_in[3];
    const float* Wk    = (const float*)d_in[4];
    const float* Wv    = (const float*)d_in[5];
    const float* Wb    = (const float*)d_in[6];
    const float* Wg    = (const float*)d_in[7];
    const float* bg    = (const float*)d_in[8];
    const float* Wo    = (const float*)d_in[9];
    const float* bo    = (const float*)d_in[10];
    float* out = (float*)d_out;

    unsigned short* Qp  = (unsigned short*)d_ws;          // 8388608 bf16
    unsigned short* Kp  = Qp + 8388608;                   // 8388608 bf16
    unsigned short* VTp = Kp + 8388608;                   // 8388608 bf16
    float* Gp   = (float*)(VTp + 8388608);                // 8388608 f32
    float* Bp   = Gp + 8388608;                           // 262144 f32
    unsigned short* AOp = (unsigned short*)(Bp + 262144); // 8388608 bf16

    k_ln_proj<<<1024, 256, 0, stream>>>(x, gamma, beta, Wq, Wk, Wv, Wb, Wg, bg,
                                        Qp, Kp, VTp, Gp, Bp);
    k_attn<<<1024, 256, 0, stream>>>(Qp, Kp, VTp, Gp, Bp, AOp);
    k_out<<<1024, 256, 0, stream>>>(AOp, Wo, bo, out);
}

// Round 3
// 278.775 us; speedup vs baseline: 2.0757x; 1.0067x over previous
//
#include <hip/hip_runtime.h>
#include <hip/hip_bf16.h>
#include <math.h>

#define S 256
#define C 128
#define NH 4
#define HID 32
#define NPOS (S*S)                       // 65536
#define SCALE 0.1767766952966369f        // 1/sqrt(32)
#define LN_EPS 1e-5f

typedef short bf16x8 __attribute__((ext_vector_type(8)));
typedef float f32x4 __attribute__((ext_vector_type(4)));

__device__ __forceinline__ unsigned short f2bf(float f) {
    __hip_bfloat16 h = __float2bfloat16(f);
    return *reinterpret_cast<unsigned short*>(&h);
}
__device__ __forceinline__ unsigned int pack2(float a, float b) {
    return (unsigned int)f2bf(a) | ((unsigned int)f2bf(b) << 16);
}

// ---------------------------------------------------------------------------
// Kernel 0: one-time weight convert+transpose to bf16. WT[m][col][k], m=q,k,v,g,o
// ---------------------------------------------------------------------------
__global__ __launch_bounds__(256)
void k_prep(const float* __restrict__ Wq, const float* __restrict__ Wk,
            const float* __restrict__ Wv, const float* __restrict__ Wg,
            const float* __restrict__ Wo, unsigned short* __restrict__ WT)
{
    int idx = blockIdx.x * 256 + threadIdx.x;     // < 5120
    int m   = idx >> 10;
    int col = (idx >> 3) & 127;
    int k0  = (idx & 7) * 16;
    const float* W = (m==0) ? Wq : (m==1) ? Wk : (m==2) ? Wv : (m==3) ? Wg : Wo;
    unsigned int u[8];
    #pragma unroll
    for (int e = 0; e < 8; ++e) {
        float a = W[(k0 + 2*e    )*128 + col];
        float b = W[(k0 + 2*e + 1)*128 + col];
        u[e] = pack2(a, b);
    }
    uint4* dst = (uint4*)(WT + m*16384 + col*128 + k0);
    dst[0] = make_uint4(u[0], u[1], u[2], u[3]);
    dst[1] = make_uint4(u[4], u[5], u[6], u[7]);
}

// ---------------------------------------------------------------------------
// Kernel 1: LayerNorm + projections. Block = fixed j, 64 consecutive i.
// grid 1024 (j = blk>>2, i0 = (blk&3)*64), 256 threads.
// B-frags straight from global WT (L2-hot). One __syncthreads total.
// outputs: Q,K bf16 [n][j][i][d]; VT bf16 [n][j][d][i]; G fp32 [n][j][i][d];
//          BIAS fp32 [n][i*256+j]
// ---------------------------------------------------------------------------
__global__ __launch_bounds__(256)
void k_ln_proj(const float* __restrict__ x, const float* __restrict__ gamma,
               const float* __restrict__ beta, const float* __restrict__ Wb,
               const float* __restrict__ bg, const unsigned short* __restrict__ WT,
               unsigned short* __restrict__ Q, unsigned short* __restrict__ K,
               unsigned short* __restrict__ VT, float* __restrict__ G,
               float* __restrict__ BIAS)
{
    __shared__ unsigned short z_lds[64][136];   // [local i][chan]

    const int t    = threadIdx.x;
    const int j    = blockIdx.x >> 2;
    const int i0   = (blockIdx.x & 3) * 64;
    const int lane = t & 63, w = t >> 6;
    const int l15  = lane & 15, quad = lane >> 4;

    // ---- LayerNorm (fp32) -> z_lds bf16, vectorized writes ----
    {
        const int m  = t >> 2;           // local position 0..63 -> i = i0+m
        const int cp = t & 3;
        float v[32];
        const float4* xr = (const float4*)(x + ((size_t)(i0 + m)*256 + j)*128 + cp*32);
        float sum = 0.f, ssq = 0.f;
        #pragma unroll
        for (int q = 0; q < 8; ++q) {
            float4 f = xr[q];
            v[q*4+0]=f.x; v[q*4+1]=f.y; v[q*4+2]=f.z; v[q*4+3]=f.w;
            sum += f.x+f.y+f.z+f.w;
            ssq += f.x*f.x+f.y*f.y+f.z*f.z+f.w*f.w;
        }
        sum += __shfl_xor(sum, 1); ssq += __shfl_xor(ssq, 1);
        sum += __shfl_xor(sum, 2); ssq += __shfl_xor(ssq, 2);
        float mu  = sum * (1.f/128.f);
        float var = ssq * (1.f/128.f) - mu*mu;
        float rs  = rsqrtf(var + LN_EPS);
        uint4* zrow = (uint4*)&z_lds[m][cp*32];
        #pragma unroll
        for (int q = 0; q < 4; ++q) {
            float z0 = (v[q*8+0]-mu)*rs*gamma[cp*32+q*8+0] + beta[cp*32+q*8+0];
            float z1 = (v[q*8+1]-mu)*rs*gamma[cp*32+q*8+1] + beta[cp*32+q*8+1];
            float z2 = (v[q*8+2]-mu)*rs*gamma[cp*32+q*8+2] + beta[cp*32+q*8+2];
            float z3 = (v[q*8+3]-mu)*rs*gamma[cp*32+q*8+3] + beta[cp*32+q*8+3];
            float z4 = (v[q*8+4]-mu)*rs*gamma[cp*32+q*8+4] + beta[cp*32+q*8+4];
            float z5 = (v[q*8+5]-mu)*rs*gamma[cp*32+q*8+5] + beta[cp*32+q*8+5];
            float z6 = (v[q*8+6]-mu)*rs*gamma[cp*32+q*8+6] + beta[cp*32+q*8+6];
            float z7 = (v[q*8+7]-mu)*rs*gamma[cp*32+q*8+7] + beta[cp*32+q*8+7];
            zrow[q] = make_uint4(pack2(z0,z1), pack2(z2,z3), pack2(z4,z5), pack2(z6,z7));
        }
    }
    __syncthreads();

    // ---- bias GEMV: BIAS[n][i*256+j] = sum_k z[i][k] * Wb[k][n] ----
    {
        const int mB = t & 63, nh = t >> 6;
        const unsigned int* zr = (const unsigned int*)&z_lds[mB][0];
        float sacc = 0.f;
        #pragma unroll 8
        for (int kk = 0; kk < 64; ++kk) {
            unsigned int u = zr[kk];
            union { unsigned int x; float f; } lo, hi;
            lo.x = u << 16; hi.x = u & 0xffff0000u;
            sacc += lo.f * Wb[(2*kk)*4 + nh] + hi.f * Wb[(2*kk+1)*4 + nh];
        }
        BIAS[(size_t)nh*NPOS + (size_t)(i0 + mB)*256 + j] = sacc;
    }

    // ---- A-fragments (wave's 16 rows) ----
    bf16x8 afrag[4];
    #pragma unroll
    for (int kt = 0; kt < 4; ++kt)
        afrag[kt] = *(const bf16x8*)&z_lds[w*16 + l15][kt*32 + quad*8];

    // ---- 4 projection matrices ----
    #pragma unroll 1
    for (int mm = 0; mm < 4; ++mm) {
        const unsigned short* Wm = WT + mm*16384;
        f32x4 acc[8];
        #pragma unroll
        for (int nt = 0; nt < 8; ++nt) acc[nt] = (f32x4){0.f,0.f,0.f,0.f};
        #pragma unroll
        for (int kt = 0; kt < 4; ++kt) {
            #pragma unroll
            for (int nt = 0; nt < 8; ++nt) {
                bf16x8 b = *(const bf16x8*)(Wm + (size_t)(nt*16 + l15)*128 + kt*32 + quad*8);
                if (mm == 2)
                    acc[nt] = __builtin_amdgcn_mfma_f32_16x16x32_bf16(b, afrag[kt], acc[nt], 0, 0, 0);
                else
                    acc[nt] = __builtin_amdgcn_mfma_f32_16x16x32_bf16(afrag[kt], b, acc[nt], 0, 0, 0);
            }
        }

        if (mm == 2) {
            // V swapped: acc rows = channel, cols (l15) = position
            const int i = i0 + w*16 + l15;
            #pragma unroll
            for (int nt = 0; nt < 8; ++nt) {
                #pragma unroll
                for (int reg = 0; reg < 4; ++reg) {
                    int cc = nt*16 + quad*4 + reg;
                    int nh = cc >> 5, d = cc & 31;
                    VT[(((size_t)(nh*256 + j))*32 + d)*256 + i] = f2bf(acc[nt][reg]);
                }
            }
        } else {
            #pragma unroll
            for (int nt = 0; nt < 8; ++nt) {
                int cc = nt*16 + l15;
                int nh = cc >> 5, d = cc & 31;
                float bgv = (mm == 3) ? bg[cc] : 0.f;
                #pragma unroll
                for (int reg = 0; reg < 4; ++reg) {
                    int i = i0 + w*16 + quad*4 + reg;
                    size_t o = (((size_t)(nh*256 + j))*256 + i)*32 + d;
                    float val = acc[nt][reg];
                    if (mm == 0)      Q[o] = f2bf(val);
                    else if (mm == 1) K[o] = f2bf(val);
                    else              G[o] = 1.f/(1.f + __expf(-(val + bgv)));
                }
            }
        }
    }
}

// ---------------------------------------------------------------------------
// Kernel 2: attention per (n, j). 256 threads, 4 independent waves, no barriers.
// ---------------------------------------------------------------------------
__global__ __launch_bounds__(256)
void k_attn(const unsigned short* __restrict__ Q, const unsigned short* __restrict__ K,
            const unsigned short* __restrict__ VT, const float* __restrict__ G,
            const float* __restrict__ BIAS, unsigned short* __restrict__ AO)
{
    __shared__ unsigned short P_lds[4][16*264];   // per-wave P strip

    const int t    = threadIdx.x;
    const int n    = blockIdx.x >> 8;
    const int j    = blockIdx.x & 255;
    const int lane = t & 63, w = t >> 6;
    const int l15  = lane & 15, quad = lane >> 4;

    const size_t nb = (size_t)(n*256 + j);
    const unsigned short* qb  = Q  + nb*8192;   // [i][d]
    const unsigned short* kb  = K  + nb*8192;   // [k][d]
    const unsigned short* vtb = VT + nb*8192;   // [d][k]
    const float* gb    = G + nb*8192;           // [i][d]
    const float* biasn = BIAS + (size_t)n*NPOS; // [i][k]
    unsigned short* Pw = P_lds[w];

    #pragma unroll 1
    for (int itc = 0; itc < 4; ++itc) {
        const int i0 = w*64 + itc*16;

        bf16x8 a = *(const bf16x8*)(qb + (size_t)(i0 + l15)*32 + quad*8);
        f32x4 acc[16];
        #pragma unroll
        for (int kt = 0; kt < 16; ++kt) {
            bf16x8 b = *(const bf16x8*)(kb + (size_t)(kt*16 + l15)*32 + quad*8);
            acc[kt] = __builtin_amdgcn_mfma_f32_16x16x32_bf16(a, b, (f32x4){0.f,0.f,0.f,0.f}, 0, 0, 0);
        }

        float mx[4] = {-1e30f, -1e30f, -1e30f, -1e30f};
        #pragma unroll
        for (int kt = 0; kt < 16; ++kt) {
            #pragma unroll
            for (int reg = 0; reg < 4; ++reg) {
                float bv = biasn[(size_t)(i0 + quad*4 + reg)*256 + kt*16 + l15];
                float v = acc[kt][reg]*SCALE + bv;
                acc[kt][reg] = v;
                mx[reg] = fmaxf(mx[reg], v);
            }
        }
        #pragma unroll
        for (int m = 1; m <= 8; m <<= 1) {
            #pragma unroll
            for (int reg = 0; reg < 4; ++reg)
                mx[reg] = fmaxf(mx[reg], __shfl_xor(mx[reg], m));
        }

        float sm[4] = {0.f, 0.f, 0.f, 0.f};
        #pragma unroll
        for (int kt = 0; kt < 16; ++kt) {
            #pragma unroll
            for (int reg = 0; reg < 4; ++reg) {
                float e = __expf(acc[kt][reg] - mx[reg]);
                acc[kt][reg] = e;
                sm[reg] += e;
            }
        }
        #pragma unroll
        for (int m = 1; m <= 8; m <<= 1) {
            #pragma unroll
            for (int reg = 0; reg < 4; ++reg)
                sm[reg] += __shfl_xor(sm[reg], m);
        }
        float rinv[4];
        #pragma unroll
        for (int reg = 0; reg < 4; ++reg) rinv[reg] = 1.f / sm[reg];

        #pragma unroll
        for (int kt = 0; kt < 16; ++kt) {
            #pragma unroll
            for (int reg = 0; reg < 4; ++reg)
                Pw[(quad*4 + reg)*264 + kt*16 + l15] = f2bf(acc[kt][reg]);
        }

        f32x4 o[2];
        o[0] = (f32x4){0.f,0.f,0.f,0.f};
        o[1] = (f32x4){0.f,0.f,0.f,0.f};
        #pragma unroll
        for (int kt8 = 0; kt8 < 8; ++kt8) {
            bf16x8 pa = *(const bf16x8*)(Pw + l15*264 + kt8*32 + quad*8);
            #pragma unroll
            for (int nt = 0; nt < 2; ++nt) {
                bf16x8 vb = *(const bf16x8*)(vtb + (size_t)(nt*16 + l15)*256 + kt8*32 + quad*8);
                o[nt] = __builtin_amdgcn_mfma_f32_16x16x32_bf16(pa, vb, o[nt], 0, 0, 0);
            }
        }

        #pragma unroll
        for (int nt = 0; nt < 2; ++nt) {
            #pragma unroll
            for (int reg = 0; reg < 4; ++reg) {
                int i = i0 + quad*4 + reg;
                float g = gb[(size_t)i*32 + nt*16 + l15];
                float res = o[nt][reg] * rinv[reg] * g;
                AO[((size_t)(i*256 + j))*128 + n*32 + nt*16 + l15] = f2bf(res);
            }
        }
    }
}

// ---------------------------------------------------------------------------
// Kernel 3: out = AO(bf16) @ Wo + bo. No LDS, no barriers.
// ---------------------------------------------------------------------------
__global__ __launch_bounds__(256)
void k_out(const unsigned short* __restrict__ AO, const unsigned short* __restrict__ WOT,
           const float* __restrict__ bo, float* __restrict__ out)
{
    const int t    = threadIdx.x;
    const int p0   = blockIdx.x * 64;
    const int lane = t & 63, w = t >> 6;
    const int l15  = lane & 15, quad = lane >> 4;

    bf16x8 a[4];
    #pragma unroll
    for (int kt = 0; kt < 4; ++kt)
        a[kt] = *(const bf16x8*)(AO + (size_t)(p0 + w*16 + l15)*128 + kt*32 + quad*8);

    f32x4 acc[8];
    #pragma unroll
    for (int nt = 0; nt < 8; ++nt) acc[nt] = (f32x4){0.f,0.f,0.f,0.f};
    #pragma unroll
    for (int kt = 0; kt < 4; ++kt) {
        #pragma unroll
        for (int nt = 0; nt < 8; ++nt) {
            bf16x8 b = *(const bf16x8*)(WOT + (size_t)(nt*16 + l15)*128 + kt*32 + quad*8);
            acc[nt] = __builtin_amdgcn_mfma_f32_16x16x32_bf16(a[kt], b, acc[nt], 0, 0, 0);
        }
    }
    #pragma unroll
    for (int nt = 0; nt < 8; ++nt) {
        float bov = bo[nt*16 + l15];
        #pragma unroll
        for (int reg = 0; reg < 4; ++reg) {
            int p = p0 + w*16 + quad*4 + reg;
            out[(size_t)p*128 + nt*16 + l15] = acc[nt][reg] + bov;
        }
    }
}

// ---------------------------------------------------------------------------
extern "C" void kernel_launch(void* const* d_in, const int* in_sizes, int n_in,
                              void* d_out, int out_size, void* d_ws, size_t ws_size,
                              hipStream_t stream) {
    (void)in_sizes; (void)n_in; (void)out_size; (void)ws_size;
    const float* x     = (const float*)d_in[0];
    const float* gamma = (const float*)d_in[1];
    const float* beta  = (const float*)d_in[2];
    const float* Wq    = (const float*)d_in[3];
    const float* Wk    = (const float*)d_in[4];
    const float* Wv    = (const float*)d_in[5];
    const float* Wb    = (const float*)d_in[6];
    const float* Wg    = (const float*)d_in[7];
    const float* bg    = (const float*)d_in[8];
    const float* Wo    = (const float*)d_in[9];
    const float* bo    = (const float*)d_in[10];
    float* out = (float*)d_out;

    unsigned short* WT  = (unsigned short*)d_ws;          // 5*16384 bf16
    unsigned short* Qp  = WT + 5*16384;                   // 8388608 bf16
    unsigned short* Kp  = Qp + 8388608;
    unsigned short* VTp = Kp + 8388608;
    float* Gp   = (float*)(VTp + 8388608);                // 8388608 f32
    float* Bp   = Gp + 8388608;                           // 262144 f32
    unsigned short* AOp = (unsigned short*)(Bp + 262144); // 8388608 bf16
    unsigned short* WOT = WT + 4*16384;

    k_prep<<<20, 256, 0, stream>>>(Wq, Wk, Wv, Wg, Wo, WT);
    k_ln_proj<<<1024, 256, 0, stream>>>(x, gamma, beta, Wb, bg, WT,
                                        Qp, Kp, VTp, Gp, Bp);
    k_attn<<<1024, 256, 0, stream>>>(Qp, Kp, VTp, Gp, Bp, AOp);
    k_out<<<1024, 256, 0, stream>>>(AOp, WOT, bo, out);
}

// Round 4
// 263.605 us; speedup vs baseline: 2.1952x; 1.0575x over previous
//
#include <hip/hip_runtime.h>
#include <hip/hip_bf16.h>
#include <math.h>

#define S 256
#define C 128
#define NH 4
#define HID 32
#define NPOS (S*S)                       // 65536
#define SCALE 0.1767766952966369f        // 1/sqrt(32)
#define LN_EPS 1e-5f

typedef short bf16x8 __attribute__((ext_vector_type(8)));
typedef float f32x4 __attribute__((ext_vector_type(4)));

__device__ __forceinline__ unsigned short f2bf(float f) {
    __hip_bfloat16 h = __float2bfloat16(f);
    return *reinterpret_cast<unsigned short*>(&h);
}
__device__ __forceinline__ float bf2f(unsigned short u) {
    union { unsigned int u32; float f; } c;
    c.u32 = ((unsigned int)u) << 16;
    return c.f;
}
__device__ __forceinline__ unsigned int pack2(float a, float b) {
    return (unsigned int)f2bf(a) | ((unsigned int)f2bf(b) << 16);
}

// ---------------------------------------------------------------------------
// Kernel 0: one-time weight convert+transpose to bf16. WT[m][col][k], m=q,k,v,g,o
// ---------------------------------------------------------------------------
__global__ __launch_bounds__(256)
void k_prep(const float* __restrict__ Wq, const float* __restrict__ Wk,
            const float* __restrict__ Wv, const float* __restrict__ Wg,
            const float* __restrict__ Wo, unsigned short* __restrict__ WT)
{
    int idx = blockIdx.x * 256 + threadIdx.x;     // < 5120
    int m   = idx >> 10;
    int col = (idx >> 3) & 127;
    int k0  = (idx & 7) * 16;
    const float* W = (m==0) ? Wq : (m==1) ? Wk : (m==2) ? Wv : (m==3) ? Wg : Wo;
    unsigned int u[8];
    #pragma unroll
    for (int e = 0; e < 8; ++e) {
        float a = W[(k0 + 2*e    )*128 + col];
        float b = W[(k0 + 2*e + 1)*128 + col];
        u[e] = pack2(a, b);
    }
    uint4* dst = (uint4*)(WT + m*16384 + col*128 + k0);
    dst[0] = make_uint4(u[0], u[1], u[2], u[3]);
    dst[1] = make_uint4(u[4], u[5], u[6], u[7]);
}

// ---------------------------------------------------------------------------
// Kernel 1: LayerNorm + projections. Block = fixed j, 64 consecutive i.
// Epilogue via LDS staging -> fully coalesced dwordx4 stores.
// outputs: Q(prescaled),K bf16 [n][j][i][d]; VT bf16 [n][j][d][i];
//          G bf16 [n][j][i][d]; BIAS fp32 swizzled [n][i>>2][k][i&3]
// ---------------------------------------------------------------------------
__global__ __launch_bounds__(256)
void k_ln_proj(const float* __restrict__ x, const float* __restrict__ gamma,
               const float* __restrict__ beta, const float* __restrict__ Wb,
               const float* __restrict__ bg, const unsigned short* __restrict__ WT,
               unsigned short* __restrict__ Q, unsigned short* __restrict__ K,
               unsigned short* __restrict__ VT, unsigned short* __restrict__ G,
               float* __restrict__ BIAS)
{
    // z: [64][136]; QKG staging: [64][136]; VT staging: [128][72]
    __shared__ unsigned short sbuf[9216];

    const int t    = threadIdx.x;
    const int j    = blockIdx.x >> 2;
    const int i0   = (blockIdx.x & 3) * 64;
    const int lane = t & 63, w = t >> 6;
    const int l15  = lane & 15, quad = lane >> 4;

    // ---- LayerNorm (fp32) -> z bf16 in LDS. Interleaved read: lane cp reads
    // float4 at channel q*16+cp*4 -> 4 lanes cover 64 B contiguous. ----
    {
        const int m  = t >> 2;           // local position
        const int cp = t & 3;
        float v[32];                     // v[q*4+e] = channel q*16+cp*4+e
        const float* xr = x + ((size_t)(i0 + m)*256 + j)*128;
        float sum = 0.f, ssq = 0.f;
        #pragma unroll
        for (int q = 0; q < 8; ++q) {
            float4 f = *(const float4*)(xr + q*16 + cp*4);
            v[q*4+0]=f.x; v[q*4+1]=f.y; v[q*4+2]=f.z; v[q*4+3]=f.w;
            sum += f.x+f.y+f.z+f.w;
            ssq += f.x*f.x+f.y*f.y+f.z*f.z+f.w*f.w;
        }
        sum += __shfl_xor(sum, 1); ssq += __shfl_xor(ssq, 1);
        sum += __shfl_xor(sum, 2); ssq += __shfl_xor(ssq, 2);
        float mu  = sum * (1.f/128.f);
        float var = ssq * (1.f/128.f) - mu*mu;
        float rs  = rsqrtf(var + LN_EPS);
        #pragma unroll
        for (int q = 0; q < 8; ++q) {
            int c = q*16 + cp*4;
            float z0 = (v[q*4+0]-mu)*rs*gamma[c+0] + beta[c+0];
            float z1 = (v[q*4+1]-mu)*rs*gamma[c+1] + beta[c+1];
            float z2 = (v[q*4+2]-mu)*rs*gamma[c+2] + beta[c+2];
            float z3 = (v[q*4+3]-mu)*rs*gamma[c+3] + beta[c+3];
            *(uint2*)&sbuf[m*136 + c] = make_uint2(pack2(z0,z1), pack2(z2,z3));
        }
    }
    __syncthreads();

    // ---- bias GEMV (reads z) -> swizzled BIAS[n][i>>2][k=j][i&3] ----
    {
        const int mB = t & 63, nh = t >> 6;
        const unsigned int* zr = (const unsigned int*)&sbuf[mB*136];
        float sacc = 0.f;
        #pragma unroll 8
        for (int kk = 0; kk < 64; ++kk) {
            unsigned int u = zr[kk];
            union { unsigned int x; float f; } lo, hi;
            lo.x = u << 16; hi.x = u & 0xffff0000u;
            sacc += lo.f * Wb[(2*kk)*4 + nh] + hi.f * Wb[(2*kk+1)*4 + nh];
        }
        int i = i0 + mB;
        BIAS[nh*65536 + (i >> 2)*1024 + j*4 + (i & 3)] = sacc;
    }

    // ---- A-fragments (reads z) ----
    bf16x8 afrag[4];
    #pragma unroll
    for (int kt = 0; kt < 4; ++kt)
        afrag[kt] = *(const bf16x8*)&sbuf[(w*16 + l15)*136 + kt*32 + quad*8];
    __syncthreads();   // z dead; sbuf becomes staging

    // ---- 4 projection matrices ----
    #pragma unroll 1
    for (int mm = 0; mm < 4; ++mm) {
        const unsigned short* Wm = WT + mm*16384;
        f32x4 acc[8];
        #pragma unroll
        for (int nt = 0; nt < 8; ++nt) acc[nt] = (f32x4){0.f,0.f,0.f,0.f};
        #pragma unroll
        for (int kt = 0; kt < 4; ++kt) {
            #pragma unroll
            for (int nt = 0; nt < 8; ++nt) {
                bf16x8 b = *(const bf16x8*)(Wm + (size_t)(nt*16 + l15)*128 + kt*32 + quad*8);
                if (mm == 2)
                    acc[nt] = __builtin_amdgcn_mfma_f32_16x16x32_bf16(b, afrag[kt], acc[nt], 0, 0, 0);
                else
                    acc[nt] = __builtin_amdgcn_mfma_f32_16x16x32_bf16(afrag[kt], b, acc[nt], 0, 0, 0);
            }
        }

        // ---- stage C-tiles to LDS (bf16) ----
        if (mm == 2) {
            // swapped: rows = channel cc, cols = local i. stride 72.
            #pragma unroll
            for (int nt = 0; nt < 8; ++nt) {
                #pragma unroll
                for (int reg = 0; reg < 4; ++reg) {
                    int cc = nt*16 + quad*4 + reg;
                    sbuf[cc*72 + w*16 + l15] = f2bf(acc[nt][reg]);
                }
            }
        } else {
            #pragma unroll
            for (int nt = 0; nt < 8; ++nt) {
                int cc = nt*16 + l15;
                float bgv = (mm == 3) ? bg[cc] : 0.f;
                #pragma unroll
                for (int reg = 0; reg < 4; ++reg) {
                    int row = w*16 + quad*4 + reg;
                    float val = acc[nt][reg];
                    if (mm == 0)      val *= SCALE;                        // fold attn scale into Q
                    else if (mm == 3) val = 1.f/(1.f + __expf(-(val + bgv)));
                    sbuf[row*136 + cc] = f2bf(val);
                }
            }
        }
        __syncthreads();

        // ---- coalesced read-back + wide global stores ----
        if (mm == 2) {
            #pragma unroll
            for (int rr = 0; rr < 4; ++rr) {
                int row = rr*32 + (t >> 3);       // cc 0..127
                int o   = t & 7;                  // 8B-chunk of 64 local i
                uint4 val = *(const uint4*)&sbuf[row*72 + o*8];
                int nh = row >> 5, d = row & 31;
                *(uint4*)&VT[(((size_t)(nh*256 + j))*32 + d)*256 + i0 + o*8] = val;
            }
        } else {
            #pragma unroll
            for (int h = 0; h < 4; ++h) {
                int row = t >> 2;                 // local i 0..63
                int o   = t & 3;                  // 8-channel chunk within head
                uint4 val = *(const uint4*)&sbuf[row*136 + h*32 + o*8];
                size_t off = (((size_t)(h*256 + j))*256 + i0 + row)*32 + o*8;
                if (mm == 0)      *(uint4*)&Q[off] = val;
                else if (mm == 1) *(uint4*)&K[off] = val;
                else              *(uint4*)&G[off] = val;
            }
        }
        __syncthreads();
    }
}

// ---------------------------------------------------------------------------
// Kernel 2: attention per (n, j). 4 independent waves, no barriers.
// Q is pre-scaled; bias via coalesced float4 swizzled loads; G bf16.
// ---------------------------------------------------------------------------
__global__ __launch_bounds__(256)
void k_attn(const unsigned short* __restrict__ Q, const unsigned short* __restrict__ K,
            const unsigned short* __restrict__ VT, const unsigned short* __restrict__ G,
            const float* __restrict__ BIAS, unsigned short* __restrict__ AO)
{
    __shared__ unsigned short P_lds[4][16*264];   // per-wave P strip (AO staging reuses head)

    const int t    = threadIdx.x;
    const int n    = blockIdx.x >> 8;
    const int j    = blockIdx.x & 255;
    const int lane = t & 63, w = t >> 6;
    const int l15  = lane & 15, quad = lane >> 4;

    const size_t nb = (size_t)(n*256 + j);
    const unsigned short* qb  = Q  + nb*8192;   // [i][d], pre-scaled
    const unsigned short* kb  = K  + nb*8192;   // [k][d]
    const unsigned short* vtb = VT + nb*8192;   // [d][k]
    const unsigned short* gb  = G  + nb*8192;   // [i][d]
    const float* biasn = BIAS + n*65536;        // [i>>2][k][i&3]
    unsigned short* Pw = P_lds[w];

    #pragma unroll 1
    for (int itc = 0; itc < 4; ++itc) {
        const int i0 = w*64 + itc*16;

        bf16x8 a = *(const bf16x8*)(qb + (size_t)(i0 + l15)*32 + quad*8);
        f32x4 acc[16];
        #pragma unroll
        for (int kt = 0; kt < 16; ++kt) {
            bf16x8 b = *(const bf16x8*)(kb + (size_t)(kt*16 + l15)*32 + quad*8);
            acc[kt] = __builtin_amdgcn_mfma_f32_16x16x32_bf16(a, b, (f32x4){0.f,0.f,0.f,0.f}, 0, 0, 0);
        }

        float mx[4] = {-1e30f, -1e30f, -1e30f, -1e30f};
        #pragma unroll
        for (int kt = 0; kt < 16; ++kt) {
            float4 bv = *(const float4*)&biasn[((i0 >> 2) + quad)*1024 + (kt*16 + l15)*4];
            acc[kt][0] += bv.x; acc[kt][1] += bv.y;
            acc[kt][2] += bv.z; acc[kt][3] += bv.w;
            #pragma unroll
            for (int reg = 0; reg < 4; ++reg)
                mx[reg] = fmaxf(mx[reg], acc[kt][reg]);
        }
        #pragma unroll
        for (int m = 1; m <= 8; m <<= 1) {
            #pragma unroll
            for (int reg = 0; reg < 4; ++reg)
                mx[reg] = fmaxf(mx[reg], __shfl_xor(mx[reg], m));
        }

        float sm[4] = {0.f, 0.f, 0.f, 0.f};
        #pragma unroll
        for (int kt = 0; kt < 16; ++kt) {
            #pragma unroll
            for (int reg = 0; reg < 4; ++reg) {
                float e = __expf(acc[kt][reg] - mx[reg]);
                acc[kt][reg] = e;
                sm[reg] += e;
            }
        }
        #pragma unroll
        for (int m = 1; m <= 8; m <<= 1) {
            #pragma unroll
            for (int reg = 0; reg < 4; ++reg)
                sm[reg] += __shfl_xor(sm[reg], m);
        }
        float rinv[4];
        #pragma unroll
        for (int reg = 0; reg < 4; ++reg) rinv[reg] = 1.f / sm[reg];

        #pragma unroll
        for (int kt = 0; kt < 16; ++kt) {
            #pragma unroll
            for (int reg = 0; reg < 4; ++reg)
                Pw[(quad*4 + reg)*264 + kt*16 + l15] = f2bf(acc[kt][reg]);
        }

        f32x4 o[2];
        o[0] = (f32x4){0.f,0.f,0.f,0.f};
        o[1] = (f32x4){0.f,0.f,0.f,0.f};
        #pragma unroll
        for (int kt8 = 0; kt8 < 8; ++kt8) {
            bf16x8 pa = *(const bf16x8*)(Pw + l15*264 + kt8*32 + quad*8);
            #pragma unroll
            for (int nt = 0; nt < 2; ++nt) {
                bf16x8 vb = *(const bf16x8*)(vtb + (size_t)(nt*16 + l15)*256 + kt8*32 + quad*8);
                o[nt] = __builtin_amdgcn_mfma_f32_16x16x32_bf16(pa, vb, o[nt], 0, 0, 0);
            }
        }

        // ---- gate + normalize -> stage to LDS -> 1 coalesced dwordx4 store ----
        #pragma unroll
        for (int nt = 0; nt < 2; ++nt) {
            #pragma unroll
            for (int reg = 0; reg < 4; ++reg) {
                int i = i0 + quad*4 + reg;
                float g = bf2f(gb[(size_t)i*32 + nt*16 + l15]);
                float res = o[nt][reg] * rinv[reg] * g;
                Pw[(quad*4 + reg)*40 + nt*16 + l15] = f2bf(res);   // AO staging (P dead)
            }
        }
        {
            int row = lane >> 2, oo = lane & 3;
            uint4 val = *(const uint4*)&Pw[row*40 + oo*8];
            *(uint4*)&AO[((size_t)((i0 + row)*256 + j))*128 + n*32 + oo*8] = val;
        }
    }
}

// ---------------------------------------------------------------------------
// Kernel 3: out = AO(bf16) @ Wo + bo. No LDS, no barriers.
// ---------------------------------------------------------------------------
__global__ __launch_bounds__(256)
void k_out(const unsigned short* __restrict__ AO, const unsigned short* __restrict__ WOT,
           const float* __restrict__ bo, float* __restrict__ out)
{
    const int t    = threadIdx.x;
    const int p0   = blockIdx.x * 64;
    const int lane = t & 63, w = t >> 6;
    const int l15  = lane & 15, quad = lane >> 4;

    bf16x8 a[4];
    #pragma unroll
    for (int kt = 0; kt < 4; ++kt)
        a[kt] = *(const bf16x8*)(AO + (size_t)(p0 + w*16 + l15)*128 + kt*32 + quad*8);

    f32x4 acc[8];
    #pragma unroll
    for (int nt = 0; nt < 8; ++nt) acc[nt] = (f32x4){0.f,0.f,0.f,0.f};
    #pragma unroll
    for (int kt = 0; kt < 4; ++kt) {
        #pragma unroll
        for (int nt = 0; nt < 8; ++nt) {
            bf16x8 b = *(const bf16x8*)(WOT + (size_t)(nt*16 + l15)*128 + kt*32 + quad*8);
            acc[nt] = __builtin_amdgcn_mfma_f32_16x16x32_bf16(a[kt], b, acc[nt], 0, 0, 0);
        }
    }
    #pragma unroll
    for (int nt = 0; nt < 8; ++nt) {
        float bov = bo[nt*16 + l15];
        #pragma unroll
        for (int reg = 0; reg < 4; ++reg) {
            int p = p0 + w*16 + quad*4 + reg;
            out[(size_t)p*128 + nt*16 + l15] = acc[nt][reg] + bov;
        }
    }
}

// ---------------------------------------------------------------------------
extern "C" void kernel_launch(void* const* d_in, const int* in_sizes, int n_in,
                              void* d_out, int out_size, void* d_ws, size_t ws_size,
                              hipStream_t stream) {
    (void)in_sizes; (void)n_in; (void)out_size; (void)ws_size;
    const float* x     = (const float*)d_in[0];
    const float* gamma = (const float*)d_in[1];
    const float* beta  = (const float*)d_in[2];
    const float* Wq    = (const float*)d_in[3];
    const float* Wk    = (const float*)d_in[4];
    const float* Wv    = (const float*)d_in[5];
    const float* Wb    = (const float*)d_in[6];
    const float* Wg    = (const float*)d_in[7];
    const float* bg    = (const float*)d_in[8];
    const float* Wo    = (const float*)d_in[9];
    const float* bo    = (const float*)d_in[10];
    float* out = (float*)d_out;

    unsigned short* WT  = (unsigned short*)d_ws;          // 5*16384 bf16
    unsigned short* Qp  = WT + 5*16384;                   // 8388608 bf16 each
    unsigned short* Kp  = Qp + 8388608;
    unsigned short* VTp = Kp + 8388608;
    unsigned short* Gp  = VTp + 8388608;
    float* Bp   = (float*)(Gp + 8388608);                 // 262144 f32 (swizzled)
    unsigned short* AOp = (unsigned short*)(Bp + 262144); // 8388608 bf16
    unsigned short* WOT = WT + 4*16384;

    k_prep<<<20, 256, 0, stream>>>(Wq, Wk, Wv, Wg, Wo, WT);
    k_ln_proj<<<1024, 256, 0, stream>>>(x, gamma, beta, Wb, bg, WT,
                                        Qp, Kp, VTp, Gp, Bp);
    k_attn<<<1024, 256, 0, stream>>>(Qp, Kp, VTp, Gp, Bp, AOp);
    k_out<<<1024, 256, 0, stream>>>(AOp, WOT, bo, out);
}

// Round 6
// 262.478 us; speedup vs baseline: 2.2046x; 1.0043x over previous
//
#include <hip/hip_runtime.h>
#include <hip/hip_bf16.h>
#include <math.h>

#define S 256
#define C 128
#define NPOS (S*S)                       // 65536
#define SCALE 0.1767766952966369f        // 1/sqrt(32)
#define LN_EPS 1e-5f

typedef short bf16x8 __attribute__((ext_vector_type(8)));
typedef float f32x4 __attribute__((ext_vector_type(4)));

__device__ __forceinline__ unsigned short f2bf(float f) {
    __hip_bfloat16 h = __float2bfloat16(f);
    return *reinterpret_cast<unsigned short*>(&h);
}
__device__ __forceinline__ float bf2f(unsigned short u) {
    union { unsigned int u32; float f; } c;
    c.u32 = ((unsigned int)u) << 16;
    return c.f;
}
__device__ __forceinline__ unsigned int pack2(float a, float b) {
    return (unsigned int)f2bf(a) | ((unsigned int)f2bf(b) << 16);
}

// ---------------------------------------------------------------------------
// Kernel 0: weight convert+transpose to bf16. WT[m][col][k] m=q,k,v,g,o.
// Block 20: WbT[16][128] zero-padded (rows 4..15 = 0).
// ---------------------------------------------------------------------------
__global__ __launch_bounds__(256)
void k_prep(const float* __restrict__ Wq, const float* __restrict__ Wk,
            const float* __restrict__ Wv, const float* __restrict__ Wg,
            const float* __restrict__ Wo, const float* __restrict__ Wb,
            unsigned short* __restrict__ WT, unsigned short* __restrict__ WbT)
{
    if (blockIdx.x == 20) {
        int t = threadIdx.x;              // 256 threads: 16 rows x 16 k-chunks
        int row = t >> 4, k0 = (t & 15) * 8;
        unsigned int u[4];
        #pragma unroll
        for (int e = 0; e < 4; ++e) {
            float a = 0.f, b = 0.f;
            if (row < 4) {
                a = Wb[(k0 + 2*e    )*4 + row];
                b = Wb[(k0 + 2*e + 1)*4 + row];
            }
            u[e] = pack2(a, b);
        }
        *(uint4*)(WbT + row*128 + k0) = make_uint4(u[0], u[1], u[2], u[3]);
        return;
    }
    int idx = blockIdx.x * 256 + threadIdx.x;     // < 5120
    int m   = idx >> 10;
    int col = (idx >> 3) & 127;
    int k0  = (idx & 7) * 16;
    const float* W = (m==0) ? Wq : (m==1) ? Wk : (m==2) ? Wv : (m==3) ? Wg : Wo;
    unsigned int u[8];
    #pragma unroll
    for (int e = 0; e < 8; ++e) {
        float a = W[(k0 + 2*e    )*128 + col];
        float b = W[(k0 + 2*e + 1)*128 + col];
        u[e] = pack2(a, b);
    }
    uint4* dst = (uint4*)(WT + m*16384 + col*128 + k0);
    dst[0] = make_uint4(u[0], u[1], u[2], u[3]);
    dst[1] = make_uint4(u[4], u[5], u[6], u[7]);
}

// ---------------------------------------------------------------------------
// Kernel 1: LN + projections. ONE WAVE per block, 8192 blocks.
// blk -> j = blk>>5, half = (blk>>4)&1, itile = blk&15. Wave owns 16 rows.
// LN fully in registers -> A-frags directly. half0: Q,K. half1: V,G,bias.
// ---------------------------------------------------------------------------
__global__ __launch_bounds__(64)
void k_ln_proj(const float* __restrict__ x, const float* __restrict__ gamma,
               const float* __restrict__ beta,
               const unsigned short* __restrict__ WT,
               const unsigned short* __restrict__ WbT,
               const float* __restrict__ bg,
               unsigned short* __restrict__ Q, unsigned short* __restrict__ K,
               unsigned short* __restrict__ VT, unsigned short* __restrict__ G,
               float* __restrict__ BIAS)
{
    __shared__ unsigned short sbuf[2176];   // max(16*136, 128*16)

    const int t    = threadIdx.x;
    const int l15  = t & 15, quad = t >> 4;
    const int j    = blockIdx.x >> 5;
    const int half = (blockIdx.x >> 4) & 1;
    const int i0   = (blockIdx.x & 15) * 16;
    const int i    = i0 + l15;              // this lane's row

    // ---- LayerNorm in registers: lane owns channels quad*8 + kt*32 + e ----
    float v[32];
    {
        const float* xr = x + ((size_t)i*256 + j)*128;
        float sum = 0.f, ssq = 0.f;
        #pragma unroll
        for (int kt = 0; kt < 4; ++kt) {
            float4 f0 = *(const float4*)(xr + kt*32 + quad*8);
            float4 f1 = *(const float4*)(xr + kt*32 + quad*8 + 4);
            v[kt*8+0]=f0.x; v[kt*8+1]=f0.y; v[kt*8+2]=f0.z; v[kt*8+3]=f0.w;
            v[kt*8+4]=f1.x; v[kt*8+5]=f1.y; v[kt*8+6]=f1.z; v[kt*8+7]=f1.w;
            sum += f0.x+f0.y+f0.z+f0.w + f1.x+f1.y+f1.z+f1.w;
            ssq += f0.x*f0.x+f0.y*f0.y+f0.z*f0.z+f0.w*f0.w
                 + f1.x*f1.x+f1.y*f1.y+f1.z*f1.z+f1.w*f1.w;
        }
        sum += __shfl_xor(sum, 16); ssq += __shfl_xor(ssq, 16);
        sum += __shfl_xor(sum, 32); ssq += __shfl_xor(ssq, 32);
        float mu  = sum * (1.f/128.f);
        float var = ssq * (1.f/128.f) - mu*mu;
        float rs  = rsqrtf(var + LN_EPS);
        #pragma unroll
        for (int kt = 0; kt < 4; ++kt) {
            #pragma unroll
            for (int e = 0; e < 8; ++e) {
                int c = kt*32 + quad*8 + e;
                v[kt*8+e] = (v[kt*8+e]-mu)*rs*gamma[c] + beta[c];
            }
        }
    }
    bf16x8 afrag[4];
    #pragma unroll
    for (int kt = 0; kt < 4; ++kt)
        #pragma unroll
        for (int e = 0; e < 8; ++e)
            afrag[kt][e] = (short)f2bf(v[kt*8+e]);

    if (half == 0) {
        // ================= Q then K =================
        #pragma unroll 1
        for (int mm = 0; mm < 2; ++mm) {
            const unsigned short* Wm = WT + mm*16384;
            f32x4 acc[8];
            #pragma unroll
            for (int nt = 0; nt < 8; ++nt) acc[nt] = (f32x4){0.f,0.f,0.f,0.f};
            #pragma unroll
            for (int kt = 0; kt < 4; ++kt) {
                #pragma unroll
                for (int nt = 0; nt < 8; ++nt) {
                    bf16x8 b = *(const bf16x8*)(Wm + (size_t)(nt*16 + l15)*128 + kt*32 + quad*8);
                    acc[nt] = __builtin_amdgcn_mfma_f32_16x16x32_bf16(afrag[kt], b, acc[nt], 0, 0, 0);
                }
            }
            __syncthreads();
            #pragma unroll
            for (int nt = 0; nt < 8; ++nt) {
                int cc = nt*16 + l15;
                #pragma unroll
                for (int reg = 0; reg < 4; ++reg) {
                    float val = acc[nt][reg];
                    if (mm == 0) val *= SCALE;
                    sbuf[(quad*4 + reg)*136 + cc] = f2bf(val);
                }
            }
            __syncthreads();
            {   // coalesced: per head 1 KB contiguous
                int iL = t >> 2, c = t & 3;
                unsigned short* Dst = (mm == 0) ? Q : K;
                #pragma unroll
                for (int nh = 0; nh < 4; ++nh) {
                    uint4 val = *(const uint4*)&sbuf[iL*136 + nh*32 + c*8];
                    *(uint4*)&Dst[(((size_t)(nh*256 + j))*256 + i0 + iL)*32 + c*8] = val;
                }
            }
        }
    } else {
        // ================= V (swapped) =================
        {
            const unsigned short* Wm = WT + 2*16384;
            f32x4 acc[8];
            #pragma unroll
            for (int nt = 0; nt < 8; ++nt) acc[nt] = (f32x4){0.f,0.f,0.f,0.f};
            #pragma unroll
            for (int kt = 0; kt < 4; ++kt) {
                #pragma unroll
                for (int nt = 0; nt < 8; ++nt) {
                    bf16x8 b = *(const bf16x8*)(Wm + (size_t)(nt*16 + l15)*128 + kt*32 + quad*8);
                    acc[nt] = __builtin_amdgcn_mfma_f32_16x16x32_bf16(b, afrag[kt], acc[nt], 0, 0, 0);
                }
            }
            __syncthreads();
            #pragma unroll
            for (int nt = 0; nt < 8; ++nt)
                #pragma unroll
                for (int reg = 0; reg < 4; ++reg)
                    sbuf[(nt*16 + quad*4 + reg)*16 + l15] = f2bf(acc[nt][reg]);
            __syncthreads();
            #pragma unroll
            for (int it2 = 0; it2 < 4; ++it2) {
                int idx = it2*64 + t;
                int ch = idx >> 1, c = idx & 1;
                uint4 val = *(const uint4*)&sbuf[ch*16 + c*8];
                int nh = ch >> 5, d = ch & 31;
                *(uint4*)&VT[(((size_t)(nh*256 + j))*32 + d)*256 + i0 + c*8] = val;
            }
        }
        // ================= G =================
        {
            const unsigned short* Wm = WT + 3*16384;
            f32x4 acc[8];
            #pragma unroll
            for (int nt = 0; nt < 8; ++nt) acc[nt] = (f32x4){0.f,0.f,0.f,0.f};
            #pragma unroll
            for (int kt = 0; kt < 4; ++kt) {
                #pragma unroll
                for (int nt = 0; nt < 8; ++nt) {
                    bf16x8 b = *(const bf16x8*)(Wm + (size_t)(nt*16 + l15)*128 + kt*32 + quad*8);
                    acc[nt] = __builtin_amdgcn_mfma_f32_16x16x32_bf16(afrag[kt], b, acc[nt], 0, 0, 0);
                }
            }
            __syncthreads();
            #pragma unroll
            for (int nt = 0; nt < 8; ++nt) {
                int cc = nt*16 + l15;
                float bgv = bg[cc];
                #pragma unroll
                for (int reg = 0; reg < 4; ++reg) {
                    float val = 1.f/(1.f + __expf(-(acc[nt][reg] + bgv)));
                    sbuf[(quad*4 + reg)*136 + cc] = f2bf(val);
                }
            }
            __syncthreads();
            {
                int iL = t >> 2, c = t & 3;
                #pragma unroll
                for (int nh = 0; nh < 4; ++nh) {
                    uint4 val = *(const uint4*)&sbuf[iL*136 + nh*32 + c*8];
                    *(uint4*)&G[(((size_t)(nh*256 + j))*256 + i0 + iL)*32 + c*8] = val;
                }
            }
        }
        // ================= bias via MFMA (WbT zero-padded) =================
        {
            f32x4 bacc = (f32x4){0.f,0.f,0.f,0.f};
            #pragma unroll
            for (int kt = 0; kt < 4; ++kt) {
                bf16x8 b = *(const bf16x8*)(WbT + (size_t)l15*128 + kt*32 + quad*8);
                bacc = __builtin_amdgcn_mfma_f32_16x16x32_bf16(afrag[kt], b, bacc, 0, 0, 0);
            }
            if (l15 < 4) {
                #pragma unroll
                for (int reg = 0; reg < 4; ++reg)
                    BIAS[l15*65536 + ((i0 >> 2) + quad)*1024 + j*4 + reg] = bacc[reg];
            }
        }
    }
}

// ---------------------------------------------------------------------------
// Kernel 2: attention. grid 4096 (n, j, ichunk); wave w owns ONE 16-row tile.
// 16384 independent waves, zero barriers. P strip stride 264 (k = 256 wide!).
// ---------------------------------------------------------------------------
__global__ __launch_bounds__(256)
void k_attn(const unsigned short* __restrict__ Q, const unsigned short* __restrict__ K,
            const unsigned short* __restrict__ VT, const unsigned short* __restrict__ G,
            const float* __restrict__ BIAS, unsigned short* __restrict__ AO)
{
    __shared__ unsigned short P_lds[4][16*264];

    const int t    = threadIdx.x;
    const int n    = blockIdx.x >> 10;
    const int j    = (blockIdx.x >> 2) & 255;
    const int ic   = blockIdx.x & 3;
    const int lane = t & 63, w = t >> 6;
    const int l15  = lane & 15, quad = lane >> 4;
    const int i0   = ic*64 + w*16;

    const size_t nb = (size_t)(n*256 + j);
    const unsigned short* qb  = Q  + nb*8192;   // [i][d], pre-scaled
    const unsigned short* kb  = K  + nb*8192;   // [k][d]
    const unsigned short* vtb = VT + nb*8192;   // [d][k]
    const unsigned short* gb  = G  + nb*8192;   // [i][d]
    const float* biasn = BIAS + n*65536;        // [i>>2][k][i&3]
    unsigned short* Pw = P_lds[w];

    bf16x8 a = *(const bf16x8*)(qb + (size_t)(i0 + l15)*32 + quad*8);
    f32x4 acc[16];
    #pragma unroll
    for (int kt = 0; kt < 16; ++kt) {
        bf16x8 b = *(const bf16x8*)(kb + (size_t)(kt*16 + l15)*32 + quad*8);
        acc[kt] = __builtin_amdgcn_mfma_f32_16x16x32_bf16(a, b, (f32x4){0.f,0.f,0.f,0.f}, 0, 0, 0);
    }

    float mx[4] = {-1e30f, -1e30f, -1e30f, -1e30f};
    #pragma unroll
    for (int kt = 0; kt < 16; ++kt) {
        float4 bv = *(const float4*)&biasn[((i0 >> 2) + quad)*1024 + (kt*16 + l15)*4];
        acc[kt][0] += bv.x; acc[kt][1] += bv.y;
        acc[kt][2] += bv.z; acc[kt][3] += bv.w;
        #pragma unroll
        for (int reg = 0; reg < 4; ++reg)
            mx[reg] = fmaxf(mx[reg], acc[kt][reg]);
    }
    #pragma unroll
    for (int m = 1; m <= 8; m <<= 1) {
        #pragma unroll
        for (int reg = 0; reg < 4; ++reg)
            mx[reg] = fmaxf(mx[reg], __shfl_xor(mx[reg], m));
    }

    float sm[4] = {0.f, 0.f, 0.f, 0.f};
    #pragma unroll
    for (int kt = 0; kt < 16; ++kt) {
        #pragma unroll
        for (int reg = 0; reg < 4; ++reg) {
            float e = __expf(acc[kt][reg] - mx[reg]);
            acc[kt][reg] = e;
            sm[reg] += e;
        }
    }
    #pragma unroll
    for (int m = 1; m <= 8; m <<= 1) {
        #pragma unroll
        for (int reg = 0; reg < 4; ++reg)
            sm[reg] += __shfl_xor(sm[reg], m);
    }
    float rinv[4];
    #pragma unroll
    for (int reg = 0; reg < 4; ++reg) rinv[reg] = 1.f / sm[reg];

    #pragma unroll
    for (int kt = 0; kt < 16; ++kt) {
        #pragma unroll
        for (int reg = 0; reg < 4; ++reg)
            Pw[(quad*4 + reg)*264 + kt*16 + l15] = f2bf(acc[kt][reg]);
    }

    f32x4 o[2];
    o[0] = (f32x4){0.f,0.f,0.f,0.f};
    o[1] = (f32x4){0.f,0.f,0.f,0.f};
    #pragma unroll
    for (int kt8 = 0; kt8 < 8; ++kt8) {
        bf16x8 pa = *(const bf16x8*)(Pw + l15*264 + kt8*32 + quad*8);
        #pragma unroll
        for (int nt = 0; nt < 2; ++nt) {
            bf16x8 vb = *(const bf16x8*)(vtb + (size_t)(nt*16 + l15)*256 + kt8*32 + quad*8);
            o[nt] = __builtin_amdgcn_mfma_f32_16x16x32_bf16(pa, vb, o[nt], 0, 0, 0);
        }
    }

    // gate + normalize -> stage -> coalesced store
    #pragma unroll
    for (int nt = 0; nt < 2; ++nt) {
        #pragma unroll
        for (int reg = 0; reg < 4; ++reg) {
            int i = i0 + quad*4 + reg;
            float g = bf2f(gb[(size_t)i*32 + nt*16 + l15]);
            float res = o[nt][reg] * rinv[reg] * g;
            Pw[(quad*4 + reg)*40 + nt*16 + l15] = f2bf(res);
        }
    }
    {
        int row = lane >> 2, oo = lane & 3;
        uint4 val = *(const uint4*)&Pw[row*40 + oo*8];
        *(uint4*)&AO[((size_t)((i0 + row)*256 + j))*128 + n*32 + oo*8] = val;
    }
}

// ---------------------------------------------------------------------------
// Kernel 3: out = AO(bf16) @ Wo + bo. ONE WAVE per block, 8192 blocks.
// ---------------------------------------------------------------------------
__global__ __launch_bounds__(64)
void k_out(const unsigned short* __restrict__ AO, const unsigned short* __restrict__ WOT,
           const float* __restrict__ bo, float* __restrict__ out)
{
    const int t    = threadIdx.x;
    const int l15  = t & 15, quad = t >> 4;
    const int p0   = (blockIdx.x >> 1) * 16;
    const int cb   = (blockIdx.x & 1) * 64;

    bf16x8 a[4];
    #pragma unroll
    for (int kt = 0; kt < 4; ++kt)
        a[kt] = *(const bf16x8*)(AO + (size_t)(p0 + l15)*128 + kt*32 + quad*8);

    f32x4 acc[4];
    #pragma unroll
    for (int nt = 0; nt < 4; ++nt) acc[nt] = (f32x4){0.f,0.f,0.f,0.f};
    #pragma unroll
    for (int kt = 0; kt < 4; ++kt) {
        #pragma unroll
        for (int nt = 0; nt < 4; ++nt) {
            bf16x8 b = *(const bf16x8*)(WOT + (size_t)(cb + nt*16 + l15)*128 + kt*32 + quad*8);
            acc[nt] = __builtin_amdgcn_mfma_f32_16x16x32_bf16(a[kt], b, acc[nt], 0, 0, 0);
        }
    }
    #pragma unroll
    for (int nt = 0; nt < 4; ++nt) {
        float bov = bo[cb + nt*16 + l15];
        #pragma unroll
        for (int reg = 0; reg < 4; ++reg) {
            int p = p0 + quad*4 + reg;
            out[(size_t)p*128 + cb + nt*16 + l15] = acc[nt][reg] + bov;
        }
    }
}

// ---------------------------------------------------------------------------
extern "C" void kernel_launch(void* const* d_in, const int* in_sizes, int n_in,
                              void* d_out, int out_size, void* d_ws, size_t ws_size,
                              hipStream_t stream) {
    (void)in_sizes; (void)n_in; (void)out_size; (void)ws_size;
    const float* x     = (const float*)d_in[0];
    const float* gamma = (const float*)d_in[1];
    const float* beta  = (const float*)d_in[2];
    const float* Wq    = (const float*)d_in[3];
    const float* Wk    = (const float*)d_in[4];
    const float* Wv    = (const float*)d_in[5];
    const float* Wb    = (const float*)d_in[6];
    const float* Wg    = (const float*)d_in[7];
    const float* bg    = (const float*)d_in[8];
    const float* Wo    = (const float*)d_in[9];
    const float* bo    = (const float*)d_in[10];
    float* out = (float*)d_out;

    unsigned short* WT  = (unsigned short*)d_ws;          // 5*16384 bf16
    unsigned short* WbT = WT + 5*16384;                   // 2048 bf16
    unsigned short* Qp  = WbT + 2048;                     // 8388608 bf16 each
    unsigned short* Kp  = Qp + 8388608;
    unsigned short* VTp = Kp + 8388608;
    unsigned short* Gp  = VTp + 8388608;
    float* Bp   = (float*)(Gp + 8388608);                 // 262144 f32 (swizzled)
    unsigned short* AOp = (unsigned short*)(Bp + 262144); // 8388608 bf16
    unsigned short* WOT = WT + 4*16384;

    k_prep<<<21, 256, 0, stream>>>(Wq, Wk, Wv, Wg, Wo, Wb, WT, WbT);
    k_ln_proj<<<8192, 64, 0, stream>>>(x, gamma, beta, WT, WbT, bg,
                                       Qp, Kp, VTp, Gp, Bp);
    k_attn<<<4096, 256, 0, stream>>>(Qp, Kp, VTp, Gp, Bp, AOp);
    k_out<<<8192, 64, 0, stream>>>(AOp, WOT, bo, out);
}

// Round 8
// 224.187 us; speedup vs baseline: 2.5812x; 1.1708x over previous
//
#include <hip/hip_runtime.h>
#include <hip/hip_bf16.h>
#include <math.h>

#define SCALE 0.1767766952966369f        // 1/sqrt(32)
#define LN_EPS 1e-5f

typedef short bf16x8 __attribute__((ext_vector_type(8)));
typedef float f32x4 __attribute__((ext_vector_type(4)));

__device__ __forceinline__ unsigned short f2bf(float f) {
    __hip_bfloat16 h = __float2bfloat16(f);
    return *reinterpret_cast<unsigned short*>(&h);
}
__device__ __forceinline__ float bf2f(unsigned short u) {
    union { unsigned int u32; float f; } c;
    c.u32 = ((unsigned int)u) << 16;
    return c.f;
}
__device__ __forceinline__ unsigned int pack2(float a, float b) {
    return (unsigned int)f2bf(a) | ((unsigned int)f2bf(b) << 16);
}

// ---------------------------------------------------------------------------
// Kernel 0: weight convert+transpose to bf16. WT[m][col][k] m=q,k,v,g,o.
// Block 20: WbT[16][128] zero-padded (rows 4..15 = 0).  (round-6 proven)
// ---------------------------------------------------------------------------
__global__ __launch_bounds__(256)
void k_prep(const float* __restrict__ Wq, const float* __restrict__ Wk,
            const float* __restrict__ Wv, const float* __restrict__ Wg,
            const float* __restrict__ Wo, const float* __restrict__ Wb,
            unsigned short* __restrict__ WT, unsigned short* __restrict__ WbT)
{
    if (blockIdx.x == 20) {
        int t = threadIdx.x;
        int row = t >> 4, k0 = (t & 15) * 8;
        unsigned int u[4];
        #pragma unroll
        for (int e = 0; e < 4; ++e) {
            float a = 0.f, b = 0.f;
            if (row < 4) {
                a = Wb[(k0 + 2*e    )*4 + row];
                b = Wb[(k0 + 2*e + 1)*4 + row];
            }
            u[e] = pack2(a, b);
        }
        *(uint4*)(WbT + row*128 + k0) = make_uint4(u[0], u[1], u[2], u[3]);
        return;
    }
    int idx = blockIdx.x * 256 + threadIdx.x;     // < 5120
    int m   = idx >> 10;
    int col = (idx >> 3) & 127;
    int k0  = (idx & 7) * 16;
    const float* W = (m==0) ? Wq : (m==1) ? Wk : (m==2) ? Wv : (m==3) ? Wg : Wo;
    unsigned int u[8];
    #pragma unroll
    for (int e = 0; e < 8; ++e) {
        float a = W[(k0 + 2*e    )*128 + col];
        float b = W[(k0 + 2*e + 1)*128 + col];
        u[e] = pack2(a, b);
    }
    uint4* dst = (uint4*)(WT + m*16384 + col*128 + k0);
    dst[0] = make_uint4(u[0], u[1], u[2], u[3]);
    dst[1] = make_uint4(u[4], u[5], u[6], u[7]);
}

// ---------------------------------------------------------------------------
// Kernel 1: LN + projections, GEMM-style with W staged in LDS.
// grid 1024: j = blk>>2, i0base = (blk&3)*64. 256 thr, wave w owns one
// 16-row tile ti = i0base + w*16. W staged per (matrix, 64-col half):
// per-block W traffic 128 KB (was 128 KB *per wave*).
// ---------------------------------------------------------------------------
__global__ __launch_bounds__(256)
void k_ln_proj(const float* __restrict__ x, const float* __restrict__ gamma,
               const float* __restrict__ beta,
               const unsigned short* __restrict__ WT,
               const unsigned short* __restrict__ WbT,
               const float* __restrict__ bg,
               unsigned short* __restrict__ Q, unsigned short* __restrict__ K,
               unsigned short* __restrict__ VT, unsigned short* __restrict__ G,
               float* __restrict__ BIAS)
{
    __shared__ unsigned short Wbuf[64*136];     // staged W half  (17408 B)
    __shared__ unsigned short stg[4][2176];     // per-wave epilogue staging

    const int t    = threadIdx.x;
    const int lane = t & 63, w = t >> 6;
    const int l15  = lane & 15, quad = lane >> 4;
    const int j    = blockIdx.x >> 2;
    const int ti   = (blockIdx.x & 3) * 64 + w*16;   // this wave's 16 rows
    unsigned short* sw = stg[w];

    // ---- LayerNorm in registers (rows ti+l15, column j) ----
    float v[32];
    {
        const float* xr = x + ((size_t)(ti + l15)*256 + j)*128;
        float sum = 0.f, ssq = 0.f;
        #pragma unroll
        for (int kt = 0; kt < 4; ++kt) {
            float4 f0 = *(const float4*)(xr + kt*32 + quad*8);
            float4 f1 = *(const float4*)(xr + kt*32 + quad*8 + 4);
            v[kt*8+0]=f0.x; v[kt*8+1]=f0.y; v[kt*8+2]=f0.z; v[kt*8+3]=f0.w;
            v[kt*8+4]=f1.x; v[kt*8+5]=f1.y; v[kt*8+6]=f1.z; v[kt*8+7]=f1.w;
            sum += f0.x+f0.y+f0.z+f0.w + f1.x+f1.y+f1.z+f1.w;
            ssq += f0.x*f0.x+f0.y*f0.y+f0.z*f0.z+f0.w*f0.w
                 + f1.x*f1.x+f1.y*f1.y+f1.z*f1.z+f1.w*f1.w;
        }
        sum += __shfl_xor(sum, 16); ssq += __shfl_xor(ssq, 16);
        sum += __shfl_xor(sum, 32); ssq += __shfl_xor(ssq, 32);
        float mu  = sum * (1.f/128.f);
        float var = ssq * (1.f/128.f) - mu*mu;
        float rs  = rsqrtf(var + LN_EPS);
        #pragma unroll
        for (int kt = 0; kt < 4; ++kt)
            #pragma unroll
            for (int e = 0; e < 8; ++e) {
                int c = kt*32 + quad*8 + e;
                v[kt*8+e] = (v[kt*8+e]-mu)*rs*gamma[c] + beta[c];
            }
    }
    bf16x8 afrag[4];
    #pragma unroll
    for (int kt = 0; kt < 4; ++kt)
        #pragma unroll
        for (int e = 0; e < 8; ++e)
            afrag[kt][e] = (short)f2bf(v[kt*8+e]);

    // ---- bias via MFMA with zero-padded WbT (global, tiny) ----
    {
        f32x4 bacc = (f32x4){0.f,0.f,0.f,0.f};
        #pragma unroll
        for (int kt = 0; kt < 4; ++kt) {
            bf16x8 b = *(const bf16x8*)(WbT + (size_t)l15*128 + kt*32 + quad*8);
            bacc = __builtin_amdgcn_mfma_f32_16x16x32_bf16(afrag[kt], b, bacc, 0, 0, 0);
        }
        if (l15 < 4) {
            #pragma unroll
            for (int reg = 0; reg < 4; ++reg)
                BIAS[l15*65536 + ((ti >> 2) + quad)*1024 + j*4 + reg] = bacc[reg];
        }
    }

    // ---- 4 projection matrices, W through LDS in 64-col halves ----
    #pragma unroll 1
    for (int mm = 0; mm < 4; ++mm) {
        f32x4 acc[8];
        #pragma unroll
        for (int nt = 0; nt < 8; ++nt) acc[nt] = (f32x4){0.f,0.f,0.f,0.f};

        #pragma unroll 1
        for (int half = 0; half < 2; ++half) {
            __syncthreads();   // Wbuf free of previous phase's readers
            #pragma unroll
            for (int r = 0; r < 4; ++r) {
                int idx = r*256 + t;               // 1024 8-short chunks
                int col = idx >> 4, kc = idx & 15;
                *(uint4*)&Wbuf[col*136 + kc*8] =
                    *(const uint4*)&WT[mm*16384 + (half*64 + col)*128 + kc*8];
            }
            __syncthreads();

            #pragma unroll
            for (int kt = 0; kt < 4; ++kt) {
                #pragma unroll
                for (int nt2 = 0; nt2 < 4; ++nt2) {
                    bf16x8 b = *(const bf16x8*)&Wbuf[(nt2*16 + l15)*136 + kt*32 + quad*8];
                    if (mm == 2)
                        acc[half*4 + nt2] = __builtin_amdgcn_mfma_f32_16x16x32_bf16(
                            b, afrag[kt], acc[half*4 + nt2], 0, 0, 0);
                    else
                        acc[half*4 + nt2] = __builtin_amdgcn_mfma_f32_16x16x32_bf16(
                            afrag[kt], b, acc[half*4 + nt2], 0, 0, 0);
                }
            }
        }

        // ---- epilogue (per-wave staging, round-6 pattern) ----
        if (mm == 2) {
            // V swapped: rows = channel cc, cols = local position l15
            #pragma unroll
            for (int nt = 0; nt < 8; ++nt)
                #pragma unroll
                for (int reg = 0; reg < 4; ++reg)
                    sw[(nt*16 + quad*4 + reg)*16 + l15] = f2bf(acc[nt][reg]);
            #pragma unroll
            for (int it = 0; it < 4; ++it) {
                int idx = it*64 + lane;
                int ch = idx >> 1, c = idx & 1;
                uint4 val = *(const uint4*)&sw[ch*16 + c*8];
                int nh = ch >> 5, d = ch & 31;
                *(uint4*)&VT[(((size_t)(nh*256 + j))*32 + d)*256 + ti + c*8] = val;
            }
        } else {
            #pragma unroll
            for (int nt = 0; nt < 8; ++nt) {
                int cc = nt*16 + l15;
                float bgv = (mm == 3) ? bg[cc] : 0.f;
                #pragma unroll
                for (int reg = 0; reg < 4; ++reg) {
                    float val = acc[nt][reg];
                    if (mm == 0)      val *= SCALE;
                    else if (mm == 3) val = 1.f/(1.f + __expf(-(val + bgv)));
                    sw[(quad*4 + reg)*136 + cc] = f2bf(val);
                }
            }
            {
                int row = lane >> 2, c = lane & 3;
                unsigned short* Dst = (mm == 0) ? Q : (mm == 1) ? K : G;
                #pragma unroll
                for (int nh = 0; nh < 4; ++nh) {
                    uint4 val = *(const uint4*)&sw[row*136 + nh*32 + c*8];
                    *(uint4*)&Dst[(((size_t)(nh*256 + j))*256 + ti + row)*32 + c*8] = val;
                }
            }
        }
    }
}

// ---------------------------------------------------------------------------
// Kernel 2: attention. grid 4096 (n, j, ichunk); wave w owns ONE 16-row tile.
// 16384 independent waves, zero barriers. (round-6 proven)
// ---------------------------------------------------------------------------
__global__ __launch_bounds__(256)
void k_attn(const unsigned short* __restrict__ Q, const unsigned short* __restrict__ K,
            const unsigned short* __restrict__ VT, const unsigned short* __restrict__ G,
            const float* __restrict__ BIAS, unsigned short* __restrict__ AO)
{
    __shared__ unsigned short P_lds[4][16*264];

    const int t    = threadIdx.x;
    const int n    = blockIdx.x >> 10;
    const int j    = (blockIdx.x >> 2) & 255;
    const int ic   = blockIdx.x & 3;
    const int lane = t & 63, w = t >> 6;
    const int l15  = lane & 15, quad = lane >> 4;
    const int i0   = ic*64 + w*16;

    const size_t nb = (size_t)(n*256 + j);
    const unsigned short* qb  = Q  + nb*8192;   // [i][d], pre-scaled
    const unsigned short* kb  = K  + nb*8192;   // [k][d]
    const unsigned short* vtb = VT + nb*8192;   // [d][k]
    const unsigned short* gb  = G  + nb*8192;   // [i][d]
    const float* biasn = BIAS + n*65536;        // [i>>2][k][i&3]
    unsigned short* Pw = P_lds[w];

    bf16x8 a = *(const bf16x8*)(qb + (size_t)(i0 + l15)*32 + quad*8);
    f32x4 acc[16];
    #pragma unroll
    for (int kt = 0; kt < 16; ++kt) {
        bf16x8 b = *(const bf16x8*)(kb + (size_t)(kt*16 + l15)*32 + quad*8);
        acc[kt] = __builtin_amdgcn_mfma_f32_16x16x32_bf16(a, b, (f32x4){0.f,0.f,0.f,0.f}, 0, 0, 0);
    }

    float mx[4] = {-1e30f, -1e30f, -1e30f, -1e30f};
    #pragma unroll
    for (int kt = 0; kt < 16; ++kt) {
        float4 bv = *(const float4*)&biasn[((i0 >> 2) + quad)*1024 + (kt*16 + l15)*4];
        acc[kt][0] += bv.x; acc[kt][1] += bv.y;
        acc[kt][2] += bv.z; acc[kt][3] += bv.w;
        #pragma unroll
        for (int reg = 0; reg < 4; ++reg)
            mx[reg] = fmaxf(mx[reg], acc[kt][reg]);
    }
    #pragma unroll
    for (int m = 1; m <= 8; m <<= 1) {
        #pragma unroll
        for (int reg = 0; reg < 4; ++reg)
            mx[reg] = fmaxf(mx[reg], __shfl_xor(mx[reg], m));
    }

    float sm[4] = {0.f, 0.f, 0.f, 0.f};
    #pragma unroll
    for (int kt = 0; kt < 16; ++kt) {
        #pragma unroll
        for (int reg = 0; reg < 4; ++reg) {
            float e = __expf(acc[kt][reg] - mx[reg]);
            acc[kt][reg] = e;
            sm[reg] += e;
        }
    }
    #pragma unroll
    for (int m = 1; m <= 8; m <<= 1) {
        #pragma unroll
        for (int reg = 0; reg < 4; ++reg)
            sm[reg] += __shfl_xor(sm[reg], m);
    }
    float rinv[4];
    #pragma unroll
    for (int reg = 0; reg < 4; ++reg) rinv[reg] = 1.f / sm[reg];

    #pragma unroll
    for (int kt = 0; kt < 16; ++kt) {
        #pragma unroll
        for (int reg = 0; reg < 4; ++reg)
            Pw[(quad*4 + reg)*264 + kt*16 + l15] = f2bf(acc[kt][reg]);
    }

    f32x4 o[2];
    o[0] = (f32x4){0.f,0.f,0.f,0.f};
    o[1] = (f32x4){0.f,0.f,0.f,0.f};
    #pragma unroll
    for (int kt8 = 0; kt8 < 8; ++kt8) {
        bf16x8 pa = *(const bf16x8*)(Pw + l15*264 + kt8*32 + quad*8);
        #pragma unroll
        for (int nt = 0; nt < 2; ++nt) {
            bf16x8 vb = *(const bf16x8*)(vtb + (size_t)(nt*16 + l15)*256 + kt8*32 + quad*8);
            o[nt] = __builtin_amdgcn_mfma_f32_16x16x32_bf16(pa, vb, o[nt], 0, 0, 0);
        }
    }

    // gate + normalize -> stage -> coalesced store
    #pragma unroll
    for (int nt = 0; nt < 2; ++nt) {
        #pragma unroll
        for (int reg = 0; reg < 4; ++reg) {
            int i = i0 + quad*4 + reg;
            float g = bf2f(gb[(size_t)i*32 + nt*16 + l15]);
            float res = o[nt][reg] * rinv[reg] * g;
            Pw[(quad*4 + reg)*40 + nt*16 + l15] = f2bf(res);
        }
    }
    {
        int row = lane >> 2, oo = lane & 3;
        uint4 val = *(const uint4*)&Pw[row*40 + oo*8];
        *(uint4*)&AO[((size_t)((i0 + row)*256 + j))*128 + n*32 + oo*8] = val;
    }
}

// ---------------------------------------------------------------------------
// Kernel 3: out = AO(bf16) @ Wo + bo. ONE WAVE per block. (round-6 proven)
// ---------------------------------------------------------------------------
__global__ __launch_bounds__(64)
void k_out(const unsigned short* __restrict__ AO, const unsigned short* __restrict__ WOT,
           const float* __restrict__ bo, float* __restrict__ out)
{
    const int t    = threadIdx.x;
    const int l15  = t & 15, quad = t >> 4;
    const int p0   = (blockIdx.x >> 1) * 16;
    const int cb   = (blockIdx.x & 1) * 64;

    bf16x8 a[4];
    #pragma unroll
    for (int kt = 0; kt < 4; ++kt)
        a[kt] = *(const bf16x8*)(AO + (size_t)(p0 + l15)*128 + kt*32 + quad*8);

    f32x4 acc[4];
    #pragma unroll
    for (int nt = 0; nt < 4; ++nt) acc[nt] = (f32x4){0.f,0.f,0.f,0.f};
    #pragma unroll
    for (int kt = 0; kt < 4; ++kt) {
        #pragma unroll
        for (int nt = 0; nt < 4; ++nt) {
            bf16x8 b = *(const bf16x8*)(WOT + (size_t)(cb + nt*16 + l15)*128 + kt*32 + quad*8);
            acc[nt] = __builtin_amdgcn_mfma_f32_16x16x32_bf16(a[kt], b, acc[nt], 0, 0, 0);
        }
    }
    #pragma unroll
    for (int nt = 0; nt < 4; ++nt) {
        float bov = bo[cb + nt*16 + l15];
        #pragma unroll
        for (int reg = 0; reg < 4; ++reg) {
            int p = p0 + quad*4 + reg;
            out[(size_t)p*128 + cb + nt*16 + l15] = acc[nt][reg] + bov;
        }
    }
}

// ---------------------------------------------------------------------------
extern "C" void kernel_launch(void* const* d_in, const int* in_sizes, int n_in,
                              void* d_out, int out_size, void* d_ws, size_t ws_size,
                              hipStream_t stream) {
    (void)in_sizes; (void)n_in; (void)out_size; (void)ws_size;
    const float* x     = (const float*)d_in[0];
    const float* gamma = (const float*)d_in[1];
    const float* beta  = (const float*)d_in[2];
    const float* Wq    = (const float*)d_in[3];
    const float* Wk    = (const float*)d_in[4];
    const float* Wv    = (const float*)d_in[5];
    const float* Wb    = (const float*)d_in[6];
    const float* Wg    = (const float*)d_in[7];
    const float* bg    = (const float*)d_in[8];
    const float* Wo    = (const float*)d_in[9];
    const float* bo    = (const float*)d_in[10];
    float* out = (float*)d_out;

    unsigned short* WT  = (unsigned short*)d_ws;          // 5*16384 bf16
    unsigned short* WbT = WT + 5*16384;                   // 2048 bf16
    unsigned short* Qp  = WbT + 2048;                     // 8388608 bf16 each
    unsigned short* Kp  = Qp + 8388608;
    unsigned short* VTp = Kp + 8388608;
    unsigned short* Gp  = VTp + 8388608;
    float* Bp   = (float*)(Gp + 8388608);                 // 262144 f32 (swizzled)
    unsigned short* AOp = (unsigned short*)(Bp + 262144); // 8388608 bf16
    unsigned short* WOT = WT + 4*16384;

    k_prep<<<21, 256, 0, stream>>>(Wq, Wk, Wv, Wg, Wo, Wb, WT, WbT);
    k_ln_proj<<<1024, 256, 0, stream>>>(x, gamma, beta, WT, WbT, bg,
                                        Qp, Kp, VTp, Gp, Bp);
    k_attn<<<4096, 256, 0, stream>>>(Qp, Kp, VTp, Gp, Bp, AOp);
    k_out<<<8192, 64, 0, stream>>>(AOp, WOT, bo, out);
}